// Round 5
// baseline (1489.847 us; speedup 1.0000x reference)
//
#include <hip/hip_runtime.h>
#include <hip/hip_fp16.h>
#include <math.h>

typedef _Float16 f16;
typedef _Float16 f16x2 __attribute__((ext_vector_type(2)));
typedef _Float16 f16x4 __attribute__((ext_vector_type(4)));
typedef _Float16 f16x8 __attribute__((ext_vector_type(8)));
typedef float f32x4 __attribute__((ext_vector_type(4)));
typedef float f32x16 __attribute__((ext_vector_type(16)));
typedef unsigned long long u64;

// async global->LDS, 16B per lane; LDS dest must be wave-uniform base (HW adds lane*16)
#define GLD16(g, s) __builtin_amdgcn_global_load_lds( \
    (const __attribute__((address_space(1))) void*)(g), \
    (__attribute__((address_space(3))) void*)(s), 16, 0, 0)

// ---------------------------------------------------------------------------
// split fp32 -> (hi, lo) f16 pair, pre-scaled by `scale` (=256). Weights only.
// ---------------------------------------------------------------------------
__global__ __launch_bounds__(256) void split_kernel(const float* __restrict__ src,
                                                    f16* __restrict__ hi,
                                                    f16* __restrict__ lo,
                                                    long n4, float scale) {
  long stride = (long)gridDim.x * blockDim.x;
  for (long i = (long)blockIdx.x * blockDim.x + threadIdx.x; i < n4; i += stride) {
    float4 v = ((const float4*)src)[i];
    f16x4 h, l;
    float e0 = v.x * scale; f16 h0 = (f16)e0; h[0] = h0; l[0] = (f16)(e0 - (float)h0);
    float e1 = v.y * scale; f16 h1 = (f16)e1; h[1] = h1; l[1] = (f16)(e1 - (float)h1);
    float e2 = v.z * scale; f16 h2 = (f16)e2; h[2] = h2; l[2] = (f16)(e2 - (float)h2);
    float e3 = v.w * scale; f16 h3 = (f16)e3; h[3] = h3; l[3] = (f16)(e3 - (float)h3);
    ((f16x4*)hi)[i] = h;
    ((f16x4*)lo)[i] = l;
  }
}

// hi = bit-truncated x (exact in f16, pkrtz exact), lo = RNE(x - hi) (2^-22 total)
__device__ __forceinline__ void splitcvt8(f32x4 u, f32x4 v, f16x8& H, f16x8& L) {
  union { f16x2 h2[4]; f16x8 h8; } uh, ul;
#pragma unroll
  for (int p = 0; p < 2; ++p) {
    float a = u[2 * p] * 256.0f, b = u[2 * p + 1] * 256.0f;
    float am = __uint_as_float(__float_as_uint(a) & 0xFFFFE000u);
    float bm = __uint_as_float(__float_as_uint(b) & 0xFFFFE000u);
    auto pk = __builtin_amdgcn_cvt_pkrtz(am, bm);     // exact (truncated inputs)
    uh.h2[p] = *reinterpret_cast<f16x2*>(&pk);
    ul.h2[p] = (f16x2){(f16)(a - am), (f16)(b - bm)}; // RNE residual
  }
#pragma unroll
  for (int p = 0; p < 2; ++p) {
    float a = v[2 * p] * 256.0f, b = v[2 * p + 1] * 256.0f;
    float am = __uint_as_float(__float_as_uint(a) & 0xFFFFE000u);
    float bm = __uint_as_float(__float_as_uint(b) & 0xFFFFE000u);
    auto pk = __builtin_amdgcn_cvt_pkrtz(am, bm);
    uh.h2[2 + p] = *reinterpret_cast<f16x2*>(&pk);
    ul.h2[2 + p] = (f16x2){(f16)(a - am), (f16)(b - bm)};
  }
  H = uh.h8;
  L = ul.h8;
}

// ---------------------------------------------------------------------------
// Split-precision GEMM, 3-product (hi*hi + lo*hi + hi*lo), 32x32x16 MFMA.
// 256x128 tile, BK=32, 8 waves (4x2), triple-buffered LDS, depth-2 prefetch,
// counted vmcnt(6). Per wave: 2x2 32x32 output frags.
// ---------------------------------------------------------------------------
template<int EPI, int AFP32>
__global__ __launch_bounds__(512) void gemm_split(
    const void* __restrict__ Av1, const void* __restrict__ Av2,
    const f16* __restrict__ B1, const f16* __restrict__ B2,
    const float* __restrict__ bias,
    void* __restrict__ out1, void* __restrict__ out2,
    const int M, const int K) {
  __shared__ __align__(16) char smem[3][49152];
  const int tid = threadIdx.x;           // 0..511
  const int lane = tid & 63;
  const int wid = tid >> 6;              // 0..7
  const int wr = wid >> 1, wcol = wid & 1;
  const int hl = lane >> 5;              // k-half select
  const int l31 = lane & 31;
  const int m0 = blockIdx.y * 256;
  const int n0 = blockIdx.x * 128;

  f32x16 acc[2][2];
#pragma unroll
  for (int m = 0; m < 2; ++m)
#pragma unroll
    for (int n = 0; n < 2; ++n)
#pragma unroll
      for (int j = 0; j < 16; ++j) acc[m][n][j] = 0.f;

  // ---- B staging: 128x32 f16 per array, chunk-XOR (c ^ ((row>>1)&3)) ----
  const int rq = tid >> 2;
  const int cg = (((tid & 3) ^ ((tid >> 3) & 3)) * 8);
  const f16* gB1 = B1 + (size_t)(n0 + rq) * K + cg;
  const f16* gB2 = B2 + (size_t)(n0 + rq) * K + cg;

  // ---- A staging ----
  const float* gAf[4];                   // AFP32: fp32 256x32, swizzle c ^ (row&7)
  if (AFP32) {
    const float* Af = (const float*)Av1;
#pragma unroll
    for (int q = 0; q < 4; ++q) {
      int rowg = m0 + q * 64 + (tid >> 3);
      if (rowg > M - 1) rowg = M - 1;
      const int chunkg = (tid & 7) ^ ((tid >> 3) & 7);
      gAf[q] = Af + (size_t)rowg * K + chunkg * 4;
    }
  }
  const f16 *gA1q0 = nullptr, *gA1q1 = nullptr, *gA2q0 = nullptr, *gA2q1 = nullptr;
  if (!AFP32) {                          // f16 hi/lo, swizzle c ^ ((row>>1)&3)
    int ra0 = m0 + (tid >> 2);       if (ra0 > M - 1) ra0 = M - 1;
    int ra1 = m0 + 128 + (tid >> 2); if (ra1 > M - 1) ra1 = M - 1;
    gA1q0 = (const f16*)Av1 + (size_t)ra0 * K + cg;
    gA1q1 = (const f16*)Av1 + (size_t)ra1 * K + cg;
    gA2q0 = (const f16*)Av2 + (size_t)ra0 * K + cg;
    gA2q1 = (const f16*)Av2 + (size_t)ra1 * K + cg;
  }

  const int ar = wr * 64 + l31;          // A row base within tile
  const int br = wcol * 64 + l31;        // B row base within tile
  const int aswz  = ar & 7;              // fp32-A read swizzle
  const int aswz2 = (ar >> 1) & 3;       // f16-A read swizzle
  const int bswz  = (br >> 1) & 3;       // B read swizzle

  const int nt = K / 32;

#define STAGE(buf, kt)                                            \
  do {                                                            \
    char* smx_ = smem[buf];                                       \
    if (AFP32) {                                                  \
      float* db = (float*)smx_;                                   \
      GLD16(gAf[0] + (kt), db + 0 * 2048 + wid * 256);            \
      GLD16(gAf[1] + (kt), db + 1 * 2048 + wid * 256);            \
      GLD16(gAf[2] + (kt), db + 2 * 2048 + wid * 256);            \
      GLD16(gAf[3] + (kt), db + 3 * 2048 + wid * 256);            \
    } else {                                                      \
      f16* d1 = (f16*)smx_;                                       \
      f16* d2 = d1 + 8192;                                        \
      GLD16(gA1q0 + (kt), d1 + wid * 512);                        \
      GLD16(gA1q1 + (kt), d1 + 4096 + wid * 512);                 \
      GLD16(gA2q0 + (kt), d2 + wid * 512);                        \
      GLD16(gA2q1 + (kt), d2 + 4096 + wid * 512);                 \
    }                                                             \
    GLD16(gB1 + (kt), (f16*)(smx_ + 32768) + wid * 512);          \
    GLD16(gB2 + (kt), (f16*)(smx_ + 40960) + wid * 512);          \
  } while (0)

  STAGE(0, 0);
  if (nt > 1) STAGE(1, 32);
  int cur = 0;

  for (int t = 0; t < nt; ++t) {
    if (t + 1 < nt) asm volatile("s_waitcnt vmcnt(6)" ::: "memory");
    else            asm volatile("s_waitcnt vmcnt(0)" ::: "memory");
    asm volatile("s_waitcnt lgkmcnt(0)" ::: "memory");
    __builtin_amdgcn_s_barrier();
    __builtin_amdgcn_sched_barrier(0);

    int pre = cur + 2; if (pre >= 3) pre -= 3;
    if (t + 2 < nt) STAGE(pre, (t + 2) * 32);   // earliest-legal prefetch issue

    const char* smx = smem[cur];
    const f16* sb1 = (const f16*)(smx + 32768);
    const f16* sb2 = (const f16*)(smx + 40960);

    f16x8 Bh[2][2], Bl[2][2];              // [kk-half][n]
#pragma unroll
    for (int kki = 0; kki < 2; ++kki)
#pragma unroll
      for (int n = 0; n < 2; ++n) {
        const int off = (br + n * 32) * 32 + (((kki * 2 + hl) ^ bswz) * 8);
        Bh[kki][n] = *(const f16x8*)&sb1[off];
        Bl[kki][n] = *(const f16x8*)&sb2[off];
      }

    f16x8 Ah[2][2], Al[2][2];              // [kk-half][m]
    if (AFP32) {
      const float* sf = (const float*)smx;
#pragma unroll
      for (int kki = 0; kki < 2; ++kki)
#pragma unroll
        for (int m = 0; m < 2; ++m) {
          const float* rp = sf + (ar + m * 32) * 32;
          const int cu = kki * 4 + hl * 2;
          f32x4 u = *(const f32x4*)(rp + ((cu    ) ^ aswz) * 4);
          f32x4 v = *(const f32x4*)(rp + ((cu + 1) ^ aswz) * 4);
          splitcvt8(u, v, Ah[kki][m], Al[kki][m]);
        }
    } else {
      const f16* s1 = (const f16*)smx;
      const f16* s2 = s1 + 8192;
#pragma unroll
      for (int kki = 0; kki < 2; ++kki)
#pragma unroll
        for (int m = 0; m < 2; ++m) {
          const int off = (ar + m * 32) * 32 + (((kki * 2 + hl) ^ aswz2) * 8);
          Ah[kki][m] = *(const f16x8*)&s1[off];
          Al[kki][m] = *(const f16x8*)&s2[off];
        }
    }

#pragma unroll
    for (int kki = 0; kki < 2; ++kki)
#pragma unroll
      for (int m = 0; m < 2; ++m) {
        __builtin_amdgcn_s_setprio(1);
#pragma unroll
        for (int n = 0; n < 2; ++n) {
          acc[m][n] = __builtin_amdgcn_mfma_f32_32x32x16_f16(Ah[kki][m], Bh[kki][n], acc[m][n], 0, 0, 0);
          acc[m][n] = __builtin_amdgcn_mfma_f32_32x32x16_f16(Al[kki][m], Bh[kki][n], acc[m][n], 0, 0, 0);
          acc[m][n] = __builtin_amdgcn_mfma_f32_32x32x16_f16(Ah[kki][m], Bl[kki][n], acc[m][n], 0, 0, 0);
        }
        __builtin_amdgcn_s_setprio(0);
      }
    ++cur; if (cur >= 3) cur = 0;
  }
#undef STAGE

  // epilogue: 32x32 D mapping col=lane&31, row=(reg&3)+8*(reg>>2)+4*(lane>>5)
  const int crow0 = m0 + wr * 64 + 4 * hl;
#pragma unroll
  for (int n = 0; n < 2; ++n) {
    const int col = n0 + wcol * 64 + n * 32 + l31;
    const float bv = bias[col];
#pragma unroll
    for (int m = 0; m < 2; ++m) {
#pragma unroll
      for (int q = 0; q < 4; ++q)
#pragma unroll
        for (int rj = 0; rj < 4; ++rj) {
          const int row = crow0 + m * 32 + q * 8 + rj;
          if (row < M) {
            float v = acc[m][n][q * 4 + rj] * (1.0f / 65536.0f) + bv;
            v = fmaxf(v, 0.0f);
            if (EPI == 1) {
              float sv = v * 256.0f;
              f16 hh = (f16)sv;
              ((f16*)out1)[(size_t)row * 1024 + col] = hh;
              ((f16*)out2)[(size_t)row * 1024 + col] = (f16)(sv - (float)hh);
            } else {
              ((float*)out1)[(size_t)row * 1024 + col] = v;
            }
          }
        }
    }
  }
}

// ---------------------------------------------------------------------------
// Final head: c/r dots (fp32), argmax/scores, per-class delta, box decode+clip
// ---------------------------------------------------------------------------
__device__ __forceinline__ float dot4f(float4 a, float4 b) {
  return a.x * b.x + a.y * b.y + a.z * b.z + a.w * b.w;
}

__global__ __launch_bounds__(256) void head_final(
    const float* __restrict__ v7,
    const float* __restrict__ wc, const float* __restrict__ bc,
    const float* __restrict__ wr, const float* __restrict__ br,
    const float* __restrict__ rois,
    float* __restrict__ outScores, float* __restrict__ outClasses,
    float* __restrict__ outBoxes,
    float* __restrict__ smask, float* __restrict__ wsbox, int* __restrict__ wsval) {
  const int gw = (blockIdx.x * 256 + threadIdx.x) >> 6;
  const int lane = threadIdx.x & 63;
  if (gw >= 8000) return;

  const float4* vr = (const float4*)(v7 + (size_t)gw * 1024);
  float4 x0 = vr[lane], x1 = vr[64 + lane], x2 = vr[128 + lane], x3 = vr[192 + lane];

  float s[20];
#pragma unroll
  for (int o = 0; o < 20; ++o) {
    const float* wrow = (o < 4) ? (wc + o * 1024) : (wr + (o - 4) * 1024);
    const float4* w4 = (const float4*)wrow;
    float a = dot4f(x0, w4[lane]) + dot4f(x1, w4[64 + lane]) +
              dot4f(x2, w4[128 + lane]) + dot4f(x3, w4[192 + lane]);
#pragma unroll
    for (int off = 32; off >= 1; off >>= 1) a += __shfl_xor(a, off);
    s[o] = a + ((o < 4) ? bc[o] : br[o - 4]);
  }

  float best = s[0]; int cls = 0;
  if (s[1] > best) { best = s[1]; cls = 1; }
  if (s[2] > best) { best = s[2]; cls = 2; }
  if (s[3] > best) { best = s[3]; cls = 3; }

  float d0, d1, d2, d3;  // constant indices only (avoid scratch)
  if      (cls == 0) { d0 = s[4];  d1 = s[5];  d2 = s[6];  d3 = s[7];  }
  else if (cls == 1) { d0 = s[8];  d1 = s[9];  d2 = s[10]; d3 = s[11]; }
  else if (cls == 2) { d0 = s[12]; d1 = s[13]; d2 = s[14]; d3 = s[15]; }
  else               { d0 = s[16]; d1 = s[17]; d2 = s[18]; d3 = s[19]; }

  float4 rb = ((const float4*)rois)[gw];
  float w = rb.z - rb.x, h = rb.w - rb.y;
  float cx = rb.x + 0.5f * w, cy = rb.y + 0.5f * h;
  float pcx = cx + d0 * 0.1f * w;
  float pcy = cy + d1 * 0.1f * h;
  float pw = expf(d2 * 0.2f) * w;
  float ph = expf(d3 * 0.2f) * h;
  float bx0 = fminf(fmaxf(pcx - 0.5f * pw, 0.f), 512.f);
  float by0 = fminf(fmaxf(pcy - 0.5f * ph, 0.f), 512.f);
  float bx1 = fminf(fmaxf(pcx + 0.5f * pw, 0.f), 512.f);
  float by1 = fminf(fmaxf(pcy + 0.5f * ph, 0.f), 512.f);

  if (lane == 0) {
    outScores[gw] = best;
    outClasses[gw] = (float)cls;
    outBoxes[gw * 4 + 0] = bx0;
    outBoxes[gw * 4 + 1] = by0;
    outBoxes[gw * 4 + 2] = bx1;
    outBoxes[gw * 4 + 3] = by1;
    int valid = (cls != 3);
    smask[gw] = valid ? best : -INFINITY;
    wsval[gw] = valid;
    float4 bb; bb.x = bx0; bb.y = by0; bb.z = bx1; bb.w = by1;
    ((float4*)wsbox)[gw] = bb;
  }
}

// ---------------------------------------------------------------------------
// Stable descending rank (== argsort(-s) position), then scatter to sorted arrays
// ---------------------------------------------------------------------------
__global__ __launch_bounds__(256) void rank_kernel(
    const float* __restrict__ smask, const float* __restrict__ bx,
    const int* __restrict__ valid,
    int* __restrict__ order, float* __restrict__ sboxes, int* __restrict__ svalid) {
  __shared__ __align__(16) float sS[8000];
  const int tid = threadIdx.x;
  for (int i = tid; i < 8000; i += 256) sS[i] = smask[i];
  __syncthreads();
  const int i = blockIdx.x * 256 + tid;
  if (i >= 8000) return;
  const float si = sS[i];
  int cnt = 0;
  const float4* s4p = (const float4*)sS;
  for (int j4 = 0; j4 < 2000; ++j4) {
    float4 s4 = s4p[j4];
    int jb = j4 * 4;
    cnt += (s4.x > si) || (s4.x == si && (jb + 0) < i);
    cnt += (s4.y > si) || (s4.y == si && (jb + 1) < i);
    cnt += (s4.z > si) || (s4.z == si && (jb + 2) < i);
    cnt += (s4.w > si) || (s4.w == si && (jb + 3) < i);
  }
  order[cnt] = i;
  svalid[cnt] = valid[i];
  ((float4*)sboxes)[cnt] = ((const float4*)bx)[i];
}

// ---------------------------------------------------------------------------
// Suppression bitmask matrix in SORTED order; skips all-invalid tile pairs
// (same predicate as nms_scan, so no poisoned M word is ever read).
// ---------------------------------------------------------------------------
__global__ void iou_matrix(const float* __restrict__ sboxes, u64* __restrict__ M,
                           u64* __restrict__ Mdiag, const int* __restrict__ svalid) {
  const int t = blockIdx.y, w = blockIdx.x;
  if (w < t) return;
  if (svalid[t * 64] == 0 || svalid[w * 64] == 0) return;
  const int lane = threadIdx.x;
  __shared__ __align__(16) float cb[64 * 4];
  ((float4*)cb)[lane] = ((const float4*)sboxes)[w * 64 + lane];
  __syncthreads();
  const int ri = t * 64 + lane;
  float4 rb = ((const float4*)sboxes)[ri];
  const float ra = (rb.z - rb.x) * (rb.w - rb.y);
  u64 bits = 0;
  for (int j = 0; j < 64; ++j) {
    float4 c = ((float4*)cb)[j];
    float x1 = fmaxf(rb.x, c.x), y1 = fmaxf(rb.y, c.y);
    float x2 = fminf(rb.z, c.z), y2 = fminf(rb.w, c.w);
    float inter = fmaxf(x2 - x1, 0.f) * fmaxf(y2 - y1, 0.f);
    float ca = (c.z - c.x) * (c.w - c.y);
    float iou = inter / (ra + ca - inter + 1e-8f);
    int gc = w * 64 + j;
    if (iou > 0.2f && gc > ri) bits |= (1ULL << j);
  }
  M[(size_t)ri * 128 + w] = bits;
  if (w == t) Mdiag[(size_t)t * 64 + lane] = bits;
}

// ---------------------------------------------------------------------------
// Sequential greedy NMS scan, truncated to valid tiles.
// Closure: scalar-register walk via v_readlane (short SALU chain, no shfl
// round-trips). klist built by parallel prefix-popcount. OR phase unrolled 16.
// ---------------------------------------------------------------------------
__global__ __launch_bounds__(128) void nms_scan(
    const u64* __restrict__ M, const u64* __restrict__ Mdiag,
    const int* __restrict__ order,
    const int* __restrict__ svalid, float* __restrict__ outKeep) {
  __shared__ u64 acc[126];
  __shared__ unsigned char klist[64];
  __shared__ int kcount;
  __shared__ int tv[125];
  __shared__ int nvt_s;
  const int tid = threadIdx.x;
  for (int w = tid; w < 125; w += 128) acc[w] = 0;
  if (tid < 125) tv[tid] = svalid[tid * 64];
  __syncthreads();
  if (tid == 0) {
    int c = 0;
    while (c < 125 && tv[c]) ++c;
    nvt_s = c;
  }
  __syncthreads();
  const int nvt = nvt_s;

  for (int t = 0; t < nvt; ++t) {
    if (tid < 64) {  // wave 0: uniform scalar closure via readlane
      u64 myrow = Mdiag[(size_t)t * 64 + tid];  // coalesced
      unsigned mlo = (unsigned)myrow, mhi = (unsigned)(myrow >> 32);
      u64 r = acc[t];
      for (int i = 0; i < 64; ++i) {
        u64 take = ((r >> i) & 1ULL) - 1ULL;    // all-ones iff bit i clear
        unsigned rlo = (unsigned)__builtin_amdgcn_readlane((int)mlo, i);
        unsigned rhi = (unsigned)__builtin_amdgcn_readlane((int)mhi, i);
        r |= (((u64)rhi << 32) | (u64)rlo) & take;
      }
      u64 kept = ~r;
      if (tid == 0) { acc[t] = r; kcount = (int)__popcll(kept); }
      if ((kept >> tid) & 1ULL)
        klist[__popcll(kept & ((1ULL << tid) - 1ULL))] = (unsigned char)tid;
    }
    __syncthreads();
    const int kc = kcount;
    const int w = t + 1 + tid;
    if (w < nvt) {
      u64 a = acc[w];
      const u64* base = M + (size_t)t * 64 * 128 + w;
      int j = 0;
      for (; j + 16 <= kc; j += 16) {   // 16 outstanding loads
        u64 o = 0;
#pragma unroll
        for (int q = 0; q < 16; ++q) o |= base[(size_t)klist[j + q] * 128];
        a |= o;
      }
      for (; j + 4 <= kc; j += 4) {
        u64 v0 = base[(size_t)klist[j] * 128];
        u64 v1 = base[(size_t)klist[j + 1] * 128];
        u64 v2 = base[(size_t)klist[j + 2] * 128];
        u64 v3 = base[(size_t)klist[j + 3] * 128];
        a |= (v0 | v1) | (v2 | v3);
      }
      for (; j < kc; ++j) a |= base[(size_t)klist[j] * 128];
      acc[w] = a;
    }
    __syncthreads();
  }

  for (int p = tid; p < 8000; p += 128) {
    int removed = (int)((acc[p >> 6] >> (p & 63)) & 1ULL);
    float kv = (!removed && svalid[p]) ? 1.0f : 0.0f;
    outKeep[order[p]] = kv;
  }
}

// ---------------------------------------------------------------------------
extern "C" void kernel_launch(void* const* d_in, const int* in_sizes, int n_in,
                              void* d_out, int out_size, void* d_ws, size_t ws_size,
                              hipStream_t stream) {
  const float* F    = (const float*)d_in[0];
  const float* ROIS = (const float*)d_in[1];
  const float* W6   = (const float*)d_in[2];
  const float* B6   = (const float*)d_in[3];
  const float* W7   = (const float*)d_in[4];
  const float* B7   = (const float*)d_in[5];
  const float* WC   = (const float*)d_in[6];
  const float* BC   = (const float*)d_in[7];
  const float* WR   = (const float*)d_in[8];
  const float* BR   = (const float*)d_in[9];

  const size_t N = 8000, D = 12544, H = 1024;
  char* ws = (char*)d_ws;
  size_t off = 0;
  auto alloc = [&](size_t bytes) -> void* {
    void* p = (void*)(ws + off);
    off += (bytes + 255) & ~(size_t)255;
    return p;
  };
  f16*   B1w   = (f16*)alloc(H * D * 2);
  f16*   B2w   = (f16*)alloc(H * D * 2);
  f16*   V61   = (f16*)alloc(N * H * 2);
  f16*   V62   = (f16*)alloc(N * H * 2);
  f16*   W71   = (f16*)alloc(H * H * 2);
  f16*   W72   = (f16*)alloc(H * H * 2);
  float* V7    = (float*)alloc(N * H * 4);
  float* SMASK = (float*)alloc(N * 4);
  float* WSBOX = (float*)alloc(N * 16);
  int*   WSVAL = (int*)alloc(N * 4);
  int*   ORDER = (int*)alloc(N * 4);
  float* SBOX  = (float*)alloc(N * 16);
  int*   SVAL  = (int*)alloc(N * 4);
  u64*   MM    = (u64*)alloc(N * 128 * 8);
  u64*   MDIAG = (u64*)alloc(125 * 64 * 8);

  float* outScores  = (float*)d_out;
  float* outClasses = (float*)d_out + 8000;
  float* outBoxes   = (float*)d_out + 16000;
  float* outKeep    = (float*)d_out + 48000;

  split_kernel<<<1024, 256, 0, stream>>>(W6, B1w, B2w, (long)(H * D / 4), 256.0f);
  split_kernel<<<256, 256, 0, stream>>>(W7, W71, W72, (long)(H * H / 4), 256.0f);

  gemm_split<1, 1><<<dim3(8, 32), 512, 0, stream>>>(F, nullptr, B1w, B2w, B6, V61, V62, 8000, 12544);
  gemm_split<2, 0><<<dim3(8, 32), 512, 0, stream>>>(V61, V62, W71, W72, B7, V7, nullptr, 8000, 1024);

  head_final<<<2000, 256, 0, stream>>>(V7, WC, BC, WR, BR, ROIS,
                                       outScores, outClasses, outBoxes,
                                       SMASK, WSBOX, WSVAL);
  rank_kernel<<<32, 256, 0, stream>>>(SMASK, WSBOX, WSVAL, ORDER, SBOX, SVAL);
  iou_matrix<<<dim3(125, 125), 64, 0, stream>>>(SBOX, MM, MDIAG, SVAL);
  nms_scan<<<1, 128, 0, stream>>>(MM, MDIAG, ORDER, SVAL, outKeep);
}

// Round 7
// 1451.857 us; speedup vs baseline: 1.0262x; 1.0262x over previous
//
#include <hip/hip_runtime.h>
#include <hip/hip_fp16.h>
#include <math.h>

typedef _Float16 f16;
typedef _Float16 f16x4 __attribute__((ext_vector_type(4)));
typedef _Float16 f16x8 __attribute__((ext_vector_type(8)));
typedef float f32x4 __attribute__((ext_vector_type(4)));
typedef unsigned long long u64;

// async global->LDS, 16B per lane; LDS dest must be wave-uniform base (HW adds lane*16)
#define GLD16(g, s) __builtin_amdgcn_global_load_lds( \
    (const __attribute__((address_space(1))) void*)(g), \
    (__attribute__((address_space(3))) void*)(s), 16, 0, 0)

// trunc+RNE split: hi = f16(x with mantissa truncated to 13 bits) [exact cast
// in normal range], lo = RNE residual. Measured absmax 1e-3 (r5) vs 4.0 (RNE hi).
struct HL { f16 h, l; };
__device__ __forceinline__ HL split1(float e) {
  float em = __uint_as_float(__float_as_uint(e) & 0xFFFFE000u);
  f16 hh = (f16)em;
  HL r;
  r.h = hh;
  r.l = (f16)(e - (float)hh);
  return r;
}

// ---------------------------------------------------------------------------
// split fp32 -> (hi, lo) f16 pair, pre-scaled by `scale` (=256).
// ---------------------------------------------------------------------------
__global__ __launch_bounds__(256) void split_kernel(const float* __restrict__ src,
                                                    f16* __restrict__ hi,
                                                    f16* __restrict__ lo,
                                                    long n4, float scale) {
  long stride = (long)gridDim.x * blockDim.x;
  for (long i = (long)blockIdx.x * blockDim.x + threadIdx.x; i < n4; i += stride) {
    float4 v = ((const float4*)src)[i];
    f16x4 h, l;
    HL r0 = split1(v.x * scale); h[0] = r0.h; l[0] = r0.l;
    HL r1 = split1(v.y * scale); h[1] = r1.h; l[1] = r1.l;
    HL r2 = split1(v.z * scale); h[2] = r2.h; l[2] = r2.l;
    HL r3 = split1(v.w * scale); h[3] = r3.h; l[3] = r3.l;
    ((f16x4*)hi)[i] = h;
    ((f16x4*)lo)[i] = l;
  }
}

// ---------------------------------------------------------------------------
// Split-precision GEMM, 3-product (hi*hi + lo*hi + hi*lo), 16x16x32 MFMA.
// 256x128 tile, BK=32, 8 waves (4x2), triple-buffered LDS (144 KB),
// depth-2 prefetch, counted vmcnt(6). All operands pre-split f16 hi/lo with
// r2's HW-verified zero-conflict chunk-XOR pattern (16-lane groups,
// chunk ^ ((row>>1)&3)).
// ---------------------------------------------------------------------------
template<int EPI>
__global__ __launch_bounds__(512) void gemm_split(
    const f16* __restrict__ A1, const f16* __restrict__ A2,
    const f16* __restrict__ B1, const f16* __restrict__ B2,
    const float* __restrict__ bias,
    void* __restrict__ out1, void* __restrict__ out2,
    const int M, const int K) {
  // per buffer: A1 16K | A2 16K | B1 8K | B2 8K = 48 KB
  __shared__ __align__(16) char smem[3][49152];
  const int tid = threadIdx.x;           // 0..511
  const int lane = tid & 63;
  const int wid = tid >> 6;              // 0..7
  const int wr = wid >> 1, wcol = wid & 1;
  const int m0 = blockIdx.y * 256;
  const int n0 = blockIdx.x * 128;

  f32x4 acc[4][4];
#pragma unroll
  for (int m = 0; m < 4; ++m)
#pragma unroll
    for (int n = 0; n < 4; ++n) acc[m][n] = (f32x4){0.f, 0.f, 0.f, 0.f};

  // staging addresses: LDS elem e = wid*512 + lane*8 (+4096 for q1)
  // -> row = e>>5, chunk_pos = (e>>3)&3; global chunk = pos ^ ((row>>1)&3)
  const int cg = (((tid & 3) ^ ((tid >> 3) & 3)) * 8);
  int ra0 = m0 + (tid >> 2);       if (ra0 > M - 1) ra0 = M - 1;
  int ra1 = m0 + 128 + (tid >> 2); if (ra1 > M - 1) ra1 = M - 1;
  const f16* gA1q0 = A1 + (size_t)ra0 * K + cg;
  const f16* gA1q1 = A1 + (size_t)ra1 * K + cg;
  const f16* gA2q0 = A2 + (size_t)ra0 * K + cg;
  const f16* gA2q1 = A2 + (size_t)ra1 * K + cg;
  const f16* gB1 = B1 + (size_t)(n0 + (tid >> 2)) * K + cg;   // 128 rows
  const f16* gB2 = B2 + (size_t)(n0 + (tid >> 2)) * K + cg;

  const int arow = wr * 64 + (lane & 15);                    // + m*16 (m-indep swz)
  const int brow = wcol * 64 + (lane & 15);                  // + n*16
  const int kcA = (((lane >> 4) ^ ((arow >> 1) & 3)) * 8);   // r2-verified, 0 conflicts
  const int kcB = (((lane >> 4) ^ ((brow >> 1) & 3)) * 8);

  const int nt = K / 32;

#define STAGE(buf, kt)                                            \
  do {                                                            \
    char* smx_ = smem[buf];                                       \
    f16* d1 = (f16*)smx_;                                         \
    f16* d2 = d1 + 8192;                                          \
    GLD16(gA1q0 + (kt), d1 + wid * 512);                          \
    GLD16(gA1q1 + (kt), d1 + 4096 + wid * 512);                   \
    GLD16(gA2q0 + (kt), d2 + wid * 512);                          \
    GLD16(gA2q1 + (kt), d2 + 4096 + wid * 512);                   \
    GLD16(gB1 + (kt), (f16*)(smx_ + 32768) + wid * 512);          \
    GLD16(gB2 + (kt), (f16*)(smx_ + 40960) + wid * 512);          \
  } while (0)

  STAGE(0, 0);
  if (nt > 1) STAGE(1, 32);
  int cur = 0;

  for (int t = 0; t < nt; ++t) {
    // own STAGE(t) drained (6 = STAGE(t+1) still in flight); barrier makes it
    // a cross-wave guarantee. Never drains to 0 mid-loop (T4).
    if (t + 1 < nt) asm volatile("s_waitcnt vmcnt(6)" ::: "memory");
    else            asm volatile("s_waitcnt vmcnt(0)" ::: "memory");
    asm volatile("s_waitcnt lgkmcnt(0)" ::: "memory");
    __builtin_amdgcn_s_barrier();
    __builtin_amdgcn_sched_barrier(0);

    int pre = cur + 2; if (pre >= 3) pre -= 3;
    if (t + 2 < nt) STAGE(pre, (t + 2) * 32);   // earliest-legal prefetch issue

    const char* smx = smem[cur];
    const f16* s1 = (const f16*)smx;
    const f16* s2 = s1 + 8192;
    const f16* sb1 = (const f16*)(smx + 32768);
    const f16* sb2 = (const f16*)(smx + 40960);

    f16x8 a1[4], a2[4], b1[4], b2[4];
#pragma unroll
    for (int m = 0; m < 4; ++m) {
      a1[m] = *(const f16x8*)&s1[(arow + m * 16) * 32 + kcA];
      a2[m] = *(const f16x8*)&s2[(arow + m * 16) * 32 + kcA];
    }
#pragma unroll
    for (int n = 0; n < 4; ++n) {
      b1[n] = *(const f16x8*)&sb1[(brow + n * 16) * 32 + kcB];
      b2[n] = *(const f16x8*)&sb2[(brow + n * 16) * 32 + kcB];
    }

#pragma unroll
    for (int m = 0; m < 4; ++m) {
      __builtin_amdgcn_s_setprio(1);
#pragma unroll
      for (int n = 0; n < 4; ++n) {
        acc[m][n] = __builtin_amdgcn_mfma_f32_16x16x32_f16(a1[m], b1[n], acc[m][n], 0, 0, 0);
        acc[m][n] = __builtin_amdgcn_mfma_f32_16x16x32_f16(a2[m], b1[n], acc[m][n], 0, 0, 0);
        acc[m][n] = __builtin_amdgcn_mfma_f32_16x16x32_f16(a1[m], b2[n], acc[m][n], 0, 0, 0);
      }
      __builtin_amdgcn_s_setprio(0);
    }
    ++cur; if (cur >= 3) cur = 0;
  }
#undef STAGE

  // epilogue: D mapping col=lane&15, row=4*(lane>>4)+j (m89-verified)
  const int crow = m0 + wr * 64 + 4 * (lane >> 4);
  const int ccol0 = n0 + wcol * 64 + (lane & 15);
#pragma unroll
  for (int n = 0; n < 4; ++n) {
    const int col = ccol0 + n * 16;
    const float bv = bias[col];
#pragma unroll
    for (int m = 0; m < 4; ++m) {
#pragma unroll
      for (int j = 0; j < 4; ++j) {
        const int row = crow + m * 16 + j;
        if (row < M) {
          float v = acc[m][n][j] * (1.0f / 65536.0f) + bv;
          v = fmaxf(v, 0.0f);
          if (EPI == 1) {
            HL r = split1(v * 256.0f);
            ((f16*)out1)[(size_t)row * 1024 + col] = r.h;
            ((f16*)out2)[(size_t)row * 1024 + col] = r.l;
          } else {
            ((float*)out1)[(size_t)row * 1024 + col] = v;
          }
        }
      }
    }
  }
}

// ---------------------------------------------------------------------------
// Final head: c/r dots (fp32), argmax/scores, per-class delta, box decode+clip
// ---------------------------------------------------------------------------
__device__ __forceinline__ float dot4f(float4 a, float4 b) {
  return a.x * b.x + a.y * b.y + a.z * b.z + a.w * b.w;
}

__global__ __launch_bounds__(256) void head_final(
    const float* __restrict__ v7,
    const float* __restrict__ wc, const float* __restrict__ bc,
    const float* __restrict__ wr, const float* __restrict__ br,
    const float* __restrict__ rois,
    float* __restrict__ outScores, float* __restrict__ outClasses,
    float* __restrict__ outBoxes,
    float* __restrict__ smask, float* __restrict__ wsbox, int* __restrict__ wsval) {
  const int gw = (blockIdx.x * 256 + threadIdx.x) >> 6;
  const int lane = threadIdx.x & 63;
  if (gw >= 8000) return;

  const float4* vr = (const float4*)(v7 + (size_t)gw * 1024);
  float4 x0 = vr[lane], x1 = vr[64 + lane], x2 = vr[128 + lane], x3 = vr[192 + lane];

  float s[20];
#pragma unroll
  for (int o = 0; o < 20; ++o) {
    const float* wrow = (o < 4) ? (wc + o * 1024) : (wr + (o - 4) * 1024);
    const float4* w4 = (const float4*)wrow;
    float a = dot4f(x0, w4[lane]) + dot4f(x1, w4[64 + lane]) +
              dot4f(x2, w4[128 + lane]) + dot4f(x3, w4[192 + lane]);
#pragma unroll
    for (int off = 32; off >= 1; off >>= 1) a += __shfl_xor(a, off);
    s[o] = a + ((o < 4) ? bc[o] : br[o - 4]);
  }

  float best = s[0]; int cls = 0;
  if (s[1] > best) { best = s[1]; cls = 1; }
  if (s[2] > best) { best = s[2]; cls = 2; }
  if (s[3] > best) { best = s[3]; cls = 3; }

  float d0, d1, d2, d3;  // constant indices only (avoid scratch)
  if      (cls == 0) { d0 = s[4];  d1 = s[5];  d2 = s[6];  d3 = s[7];  }
  else if (cls == 1) { d0 = s[8];  d1 = s[9];  d2 = s[10]; d3 = s[11]; }
  else if (cls == 2) { d0 = s[12]; d1 = s[13]; d2 = s[14]; d3 = s[15]; }
  else               { d0 = s[16]; d1 = s[17]; d2 = s[18]; d3 = s[19]; }

  float4 rb = ((const float4*)rois)[gw];
  float w = rb.z - rb.x, h = rb.w - rb.y;
  float cx = rb.x + 0.5f * w, cy = rb.y + 0.5f * h;
  float pcx = cx + d0 * 0.1f * w;
  float pcy = cy + d1 * 0.1f * h;
  float pw = expf(d2 * 0.2f) * w;
  float ph = expf(d3 * 0.2f) * h;
  float bx0 = fminf(fmaxf(pcx - 0.5f * pw, 0.f), 512.f);
  float by0 = fminf(fmaxf(pcy - 0.5f * ph, 0.f), 512.f);
  float bx1 = fminf(fmaxf(pcx + 0.5f * pw, 0.f), 512.f);
  float by1 = fminf(fmaxf(pcy + 0.5f * ph, 0.f), 512.f);

  if (lane == 0) {
    outScores[gw] = best;
    outClasses[gw] = (float)cls;
    outBoxes[gw * 4 + 0] = bx0;
    outBoxes[gw * 4 + 1] = by0;
    outBoxes[gw * 4 + 2] = bx1;
    outBoxes[gw * 4 + 3] = by1;
    int valid = (cls != 3);
    smask[gw] = valid ? best : -INFINITY;
    wsval[gw] = valid;
    float4 bb; bb.x = bx0; bb.y = by0; bb.z = bx1; bb.w = by1;
    ((float4*)wsbox)[gw] = bb;
  }
}

// ---------------------------------------------------------------------------
// Stable descending rank (== argsort(-s) position), then scatter to sorted arrays
// ---------------------------------------------------------------------------
__global__ __launch_bounds__(256) void rank_kernel(
    const float* __restrict__ smask, const float* __restrict__ bx,
    const int* __restrict__ valid,
    int* __restrict__ order, float* __restrict__ sboxes, int* __restrict__ svalid) {
  __shared__ __align__(16) float sS[8000];
  const int tid = threadIdx.x;
  for (int i = tid; i < 8000; i += 256) sS[i] = smask[i];
  __syncthreads();
  const int i = blockIdx.x * 256 + tid;
  if (i >= 8000) return;
  const float si = sS[i];
  int cnt = 0;
  const float4* s4p = (const float4*)sS;
  for (int j4 = 0; j4 < 2000; ++j4) {
    float4 s4 = s4p[j4];
    int jb = j4 * 4;
    cnt += (s4.x > si) || (s4.x == si && (jb + 0) < i);
    cnt += (s4.y > si) || (s4.y == si && (jb + 1) < i);
    cnt += (s4.z > si) || (s4.z == si && (jb + 2) < i);
    cnt += (s4.w > si) || (s4.w == si && (jb + 3) < i);
  }
  order[cnt] = i;
  svalid[cnt] = valid[i];
  ((float4*)sboxes)[cnt] = ((const float4*)bx)[i];
}

// ---------------------------------------------------------------------------
// Suppression bitmask matrix in SORTED order; skips all-invalid tile pairs
// (same predicate as nms_scan, so no poisoned M word is ever read).
// ---------------------------------------------------------------------------
__global__ void iou_matrix(const float* __restrict__ sboxes, u64* __restrict__ M,
                           u64* __restrict__ Mdiag, const int* __restrict__ svalid) {
  const int t = blockIdx.y, w = blockIdx.x;
  if (w < t) return;
  if (svalid[t * 64] == 0 || svalid[w * 64] == 0) return;
  const int lane = threadIdx.x;
  __shared__ __align__(16) float cb[64 * 4];
  ((float4*)cb)[lane] = ((const float4*)sboxes)[w * 64 + lane];
  __syncthreads();
  const int ri = t * 64 + lane;
  float4 rb = ((const float4*)sboxes)[ri];
  const float ra = (rb.z - rb.x) * (rb.w - rb.y);
  u64 bits = 0;
  for (int j = 0; j < 64; ++j) {
    float4 c = ((float4*)cb)[j];
    float x1 = fmaxf(rb.x, c.x), y1 = fmaxf(rb.y, c.y);
    float x2 = fminf(rb.z, c.z), y2 = fminf(rb.w, c.w);
    float inter = fmaxf(x2 - x1, 0.f) * fmaxf(y2 - y1, 0.f);
    float ca = (c.z - c.x) * (c.w - c.y);
    float iou = inter / (ra + ca - inter + 1e-8f);
    int gc = w * 64 + j;
    if (iou > 0.2f && gc > ri) bits |= (1ULL << j);
  }
  M[(size_t)ri * 128 + w] = bits;
  if (w == t) Mdiag[(size_t)t * 64 + lane] = bits;
}

// ---------------------------------------------------------------------------
// Sequential greedy NMS scan, truncated to valid tiles.
// Closure: scalar walk via readlane; klist via prefix-popcount; OR unrolled 16.
// ---------------------------------------------------------------------------
__global__ __launch_bounds__(128) void nms_scan(
    const u64* __restrict__ M, const u64* __restrict__ Mdiag,
    const int* __restrict__ order,
    const int* __restrict__ svalid, float* __restrict__ outKeep) {
  __shared__ u64 acc[126];
  __shared__ unsigned char klist[64];
  __shared__ int kcount;
  __shared__ int tv[125];
  __shared__ int nvt_s;
  const int tid = threadIdx.x;
  for (int w = tid; w < 125; w += 128) acc[w] = 0;
  if (tid < 125) tv[tid] = svalid[tid * 64];
  __syncthreads();
  if (tid == 0) {
    int c = 0;
    while (c < 125 && tv[c]) ++c;
    nvt_s = c;
  }
  __syncthreads();
  const int nvt = nvt_s;

  for (int t = 0; t < nvt; ++t) {
    if (tid < 64) {  // wave 0: uniform scalar closure via readlane
      u64 myrow = Mdiag[(size_t)t * 64 + tid];  // coalesced
      unsigned mlo = (unsigned)myrow, mhi = (unsigned)(myrow >> 32);
      u64 r = acc[t];
      for (int i = 0; i < 64; ++i) {
        u64 take = ((r >> i) & 1ULL) - 1ULL;    // all-ones iff bit i clear
        unsigned rlo = (unsigned)__builtin_amdgcn_readlane((int)mlo, i);
        unsigned rhi = (unsigned)__builtin_amdgcn_readlane((int)mhi, i);
        r |= (((u64)rhi << 32) | (u64)rlo) & take;
      }
      u64 kept = ~r;
      if (tid == 0) { acc[t] = r; kcount = (int)__popcll(kept); }
      if ((kept >> tid) & 1ULL)
        klist[__popcll(kept & ((1ULL << tid) - 1ULL))] = (unsigned char)tid;
    }
    __syncthreads();
    const int kc = kcount;
    const int w = t + 1 + tid;
    if (w < nvt) {
      u64 a = acc[w];
      const u64* base = M + (size_t)t * 64 * 128 + w;
      int j = 0;
      for (; j + 16 <= kc; j += 16) {   // 16 outstanding loads
        u64 o = 0;
#pragma unroll
        for (int q = 0; q < 16; ++q) o |= base[(size_t)klist[j + q] * 128];
        a |= o;
      }
      for (; j + 4 <= kc; j += 4) {
        u64 v0 = base[(size_t)klist[j] * 128];
        u64 v1 = base[(size_t)klist[j + 1] * 128];
        u64 v2 = base[(size_t)klist[j + 2] * 128];
        u64 v3 = base[(size_t)klist[j + 3] * 128];
        a |= (v0 | v1) | (v2 | v3);
      }
      for (; j < kc; ++j) a |= base[(size_t)klist[j] * 128];
      acc[w] = a;
    }
    __syncthreads();
  }

  for (int p = tid; p < 8000; p += 128) {
    int removed = (int)((acc[p >> 6] >> (p & 63)) & 1ULL);
    float kv = (!removed && svalid[p]) ? 1.0f : 0.0f;
    outKeep[order[p]] = kv;
  }
}

// ---------------------------------------------------------------------------
extern "C" void kernel_launch(void* const* d_in, const int* in_sizes, int n_in,
                              void* d_out, int out_size, void* d_ws, size_t ws_size,
                              hipStream_t stream) {
  const float* F    = (const float*)d_in[0];
  const float* ROIS = (const float*)d_in[1];
  const float* W6   = (const float*)d_in[2];
  const float* B6   = (const float*)d_in[3];
  const float* W7   = (const float*)d_in[4];
  const float* B7   = (const float*)d_in[5];
  const float* WC   = (const float*)d_in[6];
  const float* BC   = (const float*)d_in[7];
  const float* WR   = (const float*)d_in[8];
  const float* BR   = (const float*)d_in[9];

  const size_t N = 8000, D = 12544, H = 1024;
  char* ws = (char*)d_ws;
  size_t off = 0;
  auto alloc = [&](size_t bytes) -> void* {
    void* p = (void*)(ws + off);
    off += (bytes + 255) & ~(size_t)255;
    return p;
  };
  f16*   A1    = (f16*)alloc(N * D * 2);
  f16*   A2    = (f16*)alloc(N * D * 2);
  f16*   B1w   = (f16*)alloc(H * D * 2);
  f16*   B2w   = (f16*)alloc(H * D * 2);
  f16*   V61   = (f16*)alloc(N * H * 2);
  f16*   V62   = (f16*)alloc(N * H * 2);
  f16*   W71   = (f16*)alloc(H * H * 2);
  f16*   W72   = (f16*)alloc(H * H * 2);
  float* V7    = (float*)alloc(N * H * 4);
  float* SMASK = (float*)alloc(N * 4);
  float* WSBOX = (float*)alloc(N * 16);
  int*   WSVAL = (int*)alloc(N * 4);
  int*   ORDER = (int*)alloc(N * 4);
  float* SBOX  = (float*)alloc(N * 16);
  int*   SVAL  = (int*)alloc(N * 4);
  u64*   MM    = (u64*)alloc(N * 128 * 8);
  u64*   MDIAG = (u64*)alloc(125 * 64 * 8);

  float* outScores  = (float*)d_out;
  float* outClasses = (float*)d_out + 8000;
  float* outBoxes   = (float*)d_out + 16000;
  float* outKeep    = (float*)d_out + 48000;

  split_kernel<<<2048, 256, 0, stream>>>(F, A1, A2, (long)(N * D / 4), 256.0f);
  split_kernel<<<1024, 256, 0, stream>>>(W6, B1w, B2w, (long)(H * D / 4), 256.0f);
  split_kernel<<<256, 256, 0, stream>>>(W7, W71, W72, (long)(H * H / 4), 256.0f);

  gemm_split<1><<<dim3(8, 32), 512, 0, stream>>>(A1, A2, B1w, B2w, B6, V61, V62, 8000, 12544);
  gemm_split<2><<<dim3(8, 32), 512, 0, stream>>>(V61, V62, W71, W72, B7, V7, nullptr, 8000, 1024);

  head_final<<<2000, 256, 0, stream>>>(V7, WC, BC, WR, BR, ROIS,
                                       outScores, outClasses, outBoxes,
                                       SMASK, WSBOX, WSVAL);
  rank_kernel<<<32, 256, 0, stream>>>(SMASK, WSBOX, WSVAL, ORDER, SBOX, SVAL);
  iou_matrix<<<dim3(125, 125), 64, 0, stream>>>(SBOX, MM, MDIAG, SVAL);
  nms_scan<<<1, 128, 0, stream>>>(MM, MDIAG, ORDER, SVAL, outKeep);
}

// Round 8
// 1407.814 us; speedup vs baseline: 1.0583x; 1.0313x over previous
//
#include <hip/hip_runtime.h>
#include <hip/hip_fp16.h>
#include <math.h>

typedef _Float16 f16;
typedef _Float16 f16x4 __attribute__((ext_vector_type(4)));
typedef _Float16 f16x8 __attribute__((ext_vector_type(8)));
typedef float f32x4 __attribute__((ext_vector_type(4)));
typedef unsigned long long u64;

// async global->LDS, 16B per lane; LDS dest must be wave-uniform base (HW adds lane*16)
#define GLD16(g, s) __builtin_amdgcn_global_load_lds( \
    (const __attribute__((address_space(1))) void*)(g), \
    (__attribute__((address_space(3))) void*)(s), 16, 0, 0)

// trunc+RNE split: hi = f16(x with mantissa truncated to 13 bits) [exact cast
// in normal range], lo = RNE residual. Measured absmax ~1e-3..4e-3.
struct HL { f16 h, l; };
__device__ __forceinline__ HL split1(float e) {
  float em = __uint_as_float(__float_as_uint(e) & 0xFFFFE000u);
  f16 hh = (f16)em;
  HL r;
  r.h = hh;
  r.l = (f16)(e - (float)hh);
  return r;
}

// ---------------------------------------------------------------------------
// split fp32 -> (hi, lo) f16 pair, pre-scaled by `scale` (=256). Weights only
// (F's split is fused into gemm_split<1,1>).
// ---------------------------------------------------------------------------
__global__ __launch_bounds__(256) void split_kernel(const float* __restrict__ src,
                                                    f16* __restrict__ hi,
                                                    f16* __restrict__ lo,
                                                    long n4, float scale) {
  long stride = (long)gridDim.x * blockDim.x;
  for (long i = (long)blockIdx.x * blockDim.x + threadIdx.x; i < n4; i += stride) {
    float4 v = ((const float4*)src)[i];
    f16x4 h, l;
    HL r0 = split1(v.x * scale); h[0] = r0.h; l[0] = r0.l;
    HL r1 = split1(v.y * scale); h[1] = r1.h; l[1] = r1.l;
    HL r2 = split1(v.z * scale); h[2] = r2.h; l[2] = r2.l;
    HL r3 = split1(v.w * scale); h[3] = r3.h; l[3] = r3.l;
    ((f16x4*)hi)[i] = h;
    ((f16x4*)lo)[i] = l;
  }
}

// ---------------------------------------------------------------------------
// Split-precision GEMM, 3-product (hi*hi + lo*hi + hi*lo), 16x16x32 MFMA.
// 256x128 tile, BK=32, 8 waves (4x2), triple-buffered LDS (144 KB),
// depth-2 prefetch, counted vmcnt(6).
// AFP32=1: A staged as raw fp32 (chunk-XOR c^(row&7), r3-proven), hi/lo split
//          in registers -> kills the 800MB F-split round-trip.
// AFP32=0: A pre-split f16 hi/lo, r7's zero-conflict pattern (c^((row>>1)&3)).
// ---------------------------------------------------------------------------
template<int EPI, int AFP32>
__global__ __launch_bounds__(512) void gemm_split(
    const void* __restrict__ Av1, const void* __restrict__ Av2,
    const f16* __restrict__ B1, const f16* __restrict__ B2,
    const float* __restrict__ bias,
    void* __restrict__ out1, void* __restrict__ out2,
    const int M, const int K) {
  // per buffer: A 32 KB (fp32 256x32 OR f16 hi+lo) | B1 8 KB | B2 8 KB = 48 KB
  __shared__ __align__(16) char smem[3][49152];
  const int tid = threadIdx.x;           // 0..511
  const int lane = tid & 63;
  const int wid = tid >> 6;              // 0..7
  const int wr = wid >> 1, wcol = wid & 1;
  const int m0 = blockIdx.y * 256;
  const int n0 = blockIdx.x * 128;

  f32x4 acc[4][4];
#pragma unroll
  for (int m = 0; m < 4; ++m)
#pragma unroll
    for (int n = 0; n < 4; ++n) acc[m][n] = (f32x4){0.f, 0.f, 0.f, 0.f};

  // ---- B staging (f16, r7 pattern, 0 conflicts) ----
  const int cg = (((tid & 3) ^ ((tid >> 3) & 3)) * 8);
  const f16* gB1 = B1 + (size_t)(n0 + (tid >> 2)) * K + cg;   // 128 rows
  const f16* gB2 = B2 + (size_t)(n0 + (tid >> 2)) * K + cg;

  // ---- A staging ----
  const float* gAf[4];                   // AFP32: fp32 256x32, chunk c^(row&7)
  if (AFP32) {
    const float* Af = (const float*)Av1;
#pragma unroll
    for (int q = 0; q < 4; ++q) {
      int rowg = m0 + q * 64 + (tid >> 3);
      if (rowg > M - 1) rowg = M - 1;
      const int chunkg = (tid & 7) ^ ((tid >> 3) & 7);
      gAf[q] = Af + (size_t)rowg * K + chunkg * 4;
    }
  }
  const f16 *gA1q0 = nullptr, *gA1q1 = nullptr, *gA2q0 = nullptr, *gA2q1 = nullptr;
  if (!AFP32) {
    int ra0 = m0 + (tid >> 2);       if (ra0 > M - 1) ra0 = M - 1;
    int ra1 = m0 + 128 + (tid >> 2); if (ra1 > M - 1) ra1 = M - 1;
    gA1q0 = (const f16*)Av1 + (size_t)ra0 * K + cg;
    gA1q1 = (const f16*)Av1 + (size_t)ra1 * K + cg;
    gA2q0 = (const f16*)Av2 + (size_t)ra0 * K + cg;
    gA2q1 = (const f16*)Av2 + (size_t)ra1 * K + cg;
  }

  const int arow = wr * 64 + (lane & 15);                    // + m*16 (swz m-indep)
  const int brow = wcol * 64 + (lane & 15);                  // + n*16
  const int kcA = (((lane >> 4) ^ ((arow >> 1) & 3)) * 8);   // f16-A read (0-conflict)
  const int kcB = (((lane >> 4) ^ ((brow >> 1) & 3)) * 8);
  const int pA0 = (((lane >> 4) * 2)     ^ (arow & 7)) * 4;  // fp32-A read (r3)
  const int pA1 = (((lane >> 4) * 2 + 1) ^ (arow & 7)) * 4;

  const int nt = K / 32;

#define STAGE(buf, kt)                                            \
  do {                                                            \
    char* smx_ = smem[buf];                                       \
    if (AFP32) {                                                  \
      float* db = (float*)smx_;                                   \
      GLD16(gAf[0] + (kt), db + 0 * 2048 + wid * 256);            \
      GLD16(gAf[1] + (kt), db + 1 * 2048 + wid * 256);            \
      GLD16(gAf[2] + (kt), db + 2 * 2048 + wid * 256);            \
      GLD16(gAf[3] + (kt), db + 3 * 2048 + wid * 256);            \
    } else {                                                      \
      f16* d1 = (f16*)smx_;                                       \
      f16* d2 = d1 + 8192;                                        \
      GLD16(gA1q0 + (kt), d1 + wid * 512);                        \
      GLD16(gA1q1 + (kt), d1 + 4096 + wid * 512);                 \
      GLD16(gA2q0 + (kt), d2 + wid * 512);                        \
      GLD16(gA2q1 + (kt), d2 + 4096 + wid * 512);                 \
    }                                                             \
    GLD16(gB1 + (kt), (f16*)(smx_ + 32768) + wid * 512);          \
    GLD16(gB2 + (kt), (f16*)(smx_ + 40960) + wid * 512);          \
  } while (0)
  // AFP32 staging: 4 loads of 64 rows each; both variants = 6 GLD16/thread.

  STAGE(0, 0);
  if (nt > 1) STAGE(1, 32);
  int cur = 0;

  for (int t = 0; t < nt; ++t) {
    // own STAGE(t) drained (6 = STAGE(t+1) in flight); barrier extends the
    // guarantee across waves. Never drains to 0 mid-loop (T4).
    if (t + 1 < nt) asm volatile("s_waitcnt vmcnt(6)" ::: "memory");
    else            asm volatile("s_waitcnt vmcnt(0)" ::: "memory");
    asm volatile("s_waitcnt lgkmcnt(0)" ::: "memory");
    __builtin_amdgcn_s_barrier();
    __builtin_amdgcn_sched_barrier(0);

    int pre = cur + 2; if (pre >= 3) pre -= 3;
    if (t + 2 < nt) STAGE(pre, (t + 2) * 32);   // earliest-legal prefetch

    const char* smx = smem[cur];
    f16x8 a1[4], a2[4], b1[4], b2[4];
    if (AFP32) {
      const float* sf = (const float*)smx;
#pragma unroll
      for (int m = 0; m < 4; ++m) {
        const float* rp = sf + (arow + m * 16) * 32;
        f32x4 u = *(const f32x4*)(rp + pA0);   // logical cols 8k..8k+3
        f32x4 v = *(const f32x4*)(rp + pA1);   // logical cols 8k+4..8k+7
        f16x8 h, l;
#pragma unroll
        for (int j = 0; j < 4; ++j) { HL r = split1(u[j] * 256.0f); h[j] = r.h; l[j] = r.l; }
#pragma unroll
        for (int j = 0; j < 4; ++j) { HL r = split1(v[j] * 256.0f); h[4 + j] = r.h; l[4 + j] = r.l; }
        a1[m] = h; a2[m] = l;
      }
    } else {
      const f16* s1 = (const f16*)smx;
      const f16* s2 = s1 + 8192;
#pragma unroll
      for (int m = 0; m < 4; ++m) {
        a1[m] = *(const f16x8*)&s1[(arow + m * 16) * 32 + kcA];
        a2[m] = *(const f16x8*)&s2[(arow + m * 16) * 32 + kcA];
      }
    }
    {
      const f16* sb1 = (const f16*)(smx + 32768);
      const f16* sb2 = (const f16*)(smx + 40960);
#pragma unroll
      for (int n = 0; n < 4; ++n) {
        b1[n] = *(const f16x8*)&sb1[(brow + n * 16) * 32 + kcB];
        b2[n] = *(const f16x8*)&sb2[(brow + n * 16) * 32 + kcB];
      }
    }

#pragma unroll
    for (int m = 0; m < 4; ++m) {
      __builtin_amdgcn_s_setprio(1);
#pragma unroll
      for (int n = 0; n < 4; ++n) {
        acc[m][n] = __builtin_amdgcn_mfma_f32_16x16x32_f16(a1[m], b1[n], acc[m][n], 0, 0, 0);
        acc[m][n] = __builtin_amdgcn_mfma_f32_16x16x32_f16(a2[m], b1[n], acc[m][n], 0, 0, 0);
        acc[m][n] = __builtin_amdgcn_mfma_f32_16x16x32_f16(a1[m], b2[n], acc[m][n], 0, 0, 0);
      }
      __builtin_amdgcn_s_setprio(0);
    }
    ++cur; if (cur >= 3) cur = 0;
  }
#undef STAGE

  // epilogue: D mapping col=lane&15, row=4*(lane>>4)+j (m89-verified)
  const int crow = m0 + wr * 64 + 4 * (lane >> 4);
  const int ccol0 = n0 + wcol * 64 + (lane & 15);
#pragma unroll
  for (int n = 0; n < 4; ++n) {
    const int col = ccol0 + n * 16;
    const float bv = bias[col];
#pragma unroll
    for (int m = 0; m < 4; ++m) {
#pragma unroll
      for (int j = 0; j < 4; ++j) {
        const int row = crow + m * 16 + j;
        if (row < M) {
          float v = acc[m][n][j] * (1.0f / 65536.0f) + bv;
          v = fmaxf(v, 0.0f);
          if (EPI == 1) {
            HL r = split1(v * 256.0f);
            ((f16*)out1)[(size_t)row * 1024 + col] = r.h;
            ((f16*)out2)[(size_t)row * 1024 + col] = r.l;
          } else {
            ((float*)out1)[(size_t)row * 1024 + col] = v;
          }
        }
      }
    }
  }
}

// ---------------------------------------------------------------------------
// Final head: c/r dots (fp32), argmax/scores, per-class delta, box decode+clip
// ---------------------------------------------------------------------------
__device__ __forceinline__ float dot4f(float4 a, float4 b) {
  return a.x * b.x + a.y * b.y + a.z * b.z + a.w * b.w;
}

__global__ __launch_bounds__(256) void head_final(
    const float* __restrict__ v7,
    const float* __restrict__ wc, const float* __restrict__ bc,
    const float* __restrict__ wr, const float* __restrict__ br,
    const float* __restrict__ rois,
    float* __restrict__ outScores, float* __restrict__ outClasses,
    float* __restrict__ outBoxes,
    float* __restrict__ smask, float* __restrict__ wsbox, int* __restrict__ wsval) {
  const int gw = (blockIdx.x * 256 + threadIdx.x) >> 6;
  const int lane = threadIdx.x & 63;
  if (gw >= 8000) return;

  const float4* vr = (const float4*)(v7 + (size_t)gw * 1024);
  float4 x0 = vr[lane], x1 = vr[64 + lane], x2 = vr[128 + lane], x3 = vr[192 + lane];

  float s[20];
#pragma unroll
  for (int o = 0; o < 20; ++o) {
    const float* wrow = (o < 4) ? (wc + o * 1024) : (wr + (o - 4) * 1024);
    const float4* w4 = (const float4*)wrow;
    float a = dot4f(x0, w4[lane]) + dot4f(x1, w4[64 + lane]) +
              dot4f(x2, w4[128 + lane]) + dot4f(x3, w4[192 + lane]);
#pragma unroll
    for (int off = 32; off >= 1; off >>= 1) a += __shfl_xor(a, off);
    s[o] = a + ((o < 4) ? bc[o] : br[o - 4]);
  }

  float best = s[0]; int cls = 0;
  if (s[1] > best) { best = s[1]; cls = 1; }
  if (s[2] > best) { best = s[2]; cls = 2; }
  if (s[3] > best) { best = s[3]; cls = 3; }

  float d0, d1, d2, d3;  // constant indices only (avoid scratch)
  if      (cls == 0) { d0 = s[4];  d1 = s[5];  d2 = s[6];  d3 = s[7];  }
  else if (cls == 1) { d0 = s[8];  d1 = s[9];  d2 = s[10]; d3 = s[11]; }
  else if (cls == 2) { d0 = s[12]; d1 = s[13]; d2 = s[14]; d3 = s[15]; }
  else               { d0 = s[16]; d1 = s[17]; d2 = s[18]; d3 = s[19]; }

  float4 rb = ((const float4*)rois)[gw];
  float w = rb.z - rb.x, h = rb.w - rb.y;
  float cx = rb.x + 0.5f * w, cy = rb.y + 0.5f * h;
  float pcx = cx + d0 * 0.1f * w;
  float pcy = cy + d1 * 0.1f * h;
  float pw = expf(d2 * 0.2f) * w;
  float ph = expf(d3 * 0.2f) * h;
  float bx0 = fminf(fmaxf(pcx - 0.5f * pw, 0.f), 512.f);
  float by0 = fminf(fmaxf(pcy - 0.5f * ph, 0.f), 512.f);
  float bx1 = fminf(fmaxf(pcx + 0.5f * pw, 0.f), 512.f);
  float by1 = fminf(fmaxf(pcy + 0.5f * ph, 0.f), 512.f);

  if (lane == 0) {
    outScores[gw] = best;
    outClasses[gw] = (float)cls;
    outBoxes[gw * 4 + 0] = bx0;
    outBoxes[gw * 4 + 1] = by0;
    outBoxes[gw * 4 + 2] = bx1;
    outBoxes[gw * 4 + 3] = by1;
    int valid = (cls != 3);
    smask[gw] = valid ? best : -INFINITY;
    wsval[gw] = valid;
    float4 bb; bb.x = bx0; bb.y = by0; bb.z = bx1; bb.w = by1;
    ((float4*)wsbox)[gw] = bb;
  }
}

// ---------------------------------------------------------------------------
// Stable descending rank (== argsort(-s) position), then scatter to sorted arrays
// ---------------------------------------------------------------------------
__global__ __launch_bounds__(256) void rank_kernel(
    const float* __restrict__ smask, const float* __restrict__ bx,
    const int* __restrict__ valid,
    int* __restrict__ order, float* __restrict__ sboxes, int* __restrict__ svalid) {
  __shared__ __align__(16) float sS[8000];
  const int tid = threadIdx.x;
  for (int i = tid; i < 8000; i += 256) sS[i] = smask[i];
  __syncthreads();
  const int i = blockIdx.x * 256 + tid;
  if (i >= 8000) return;
  const float si = sS[i];
  int cnt = 0;
  const float4* s4p = (const float4*)sS;
  for (int j4 = 0; j4 < 2000; ++j4) {
    float4 s4 = s4p[j4];
    int jb = j4 * 4;
    cnt += (s4.x > si) || (s4.x == si && (jb + 0) < i);
    cnt += (s4.y > si) || (s4.y == si && (jb + 1) < i);
    cnt += (s4.z > si) || (s4.z == si && (jb + 2) < i);
    cnt += (s4.w > si) || (s4.w == si && (jb + 3) < i);
  }
  order[cnt] = i;
  svalid[cnt] = valid[i];
  ((float4*)sboxes)[cnt] = ((const float4*)bx)[i];
}

// ---------------------------------------------------------------------------
// Suppression bitmask matrix in SORTED order; skips all-invalid tile pairs
// (same predicate as nms_scan, so no poisoned M word is ever read).
// ---------------------------------------------------------------------------
__global__ void iou_matrix(const float* __restrict__ sboxes, u64* __restrict__ M,
                           u64* __restrict__ Mdiag, const int* __restrict__ svalid) {
  const int t = blockIdx.y, w = blockIdx.x;
  if (w < t) return;
  if (svalid[t * 64] == 0 || svalid[w * 64] == 0) return;
  const int lane = threadIdx.x;
  __shared__ __align__(16) float cb[64 * 4];
  ((float4*)cb)[lane] = ((const float4*)sboxes)[w * 64 + lane];
  __syncthreads();
  const int ri = t * 64 + lane;
  float4 rb = ((const float4*)sboxes)[ri];
  const float ra = (rb.z - rb.x) * (rb.w - rb.y);
  u64 bits = 0;
  for (int j = 0; j < 64; ++j) {
    float4 c = ((float4*)cb)[j];
    float x1 = fmaxf(rb.x, c.x), y1 = fmaxf(rb.y, c.y);
    float x2 = fminf(rb.z, c.z), y2 = fminf(rb.w, c.w);
    float inter = fmaxf(x2 - x1, 0.f) * fmaxf(y2 - y1, 0.f);
    float ca = (c.z - c.x) * (c.w - c.y);
    float iou = inter / (ra + ca - inter + 1e-8f);
    int gc = w * 64 + j;
    if (iou > 0.2f && gc > ri) bits |= (1ULL << j);
  }
  M[(size_t)ri * 128 + w] = bits;
  if (w == t) Mdiag[(size_t)t * 64 + lane] = bits;
}

// ---------------------------------------------------------------------------
// Sequential greedy NMS scan, truncated to valid tiles. Mdiag staged fully
// in LDS upfront (64 KB) so the serial closure chain never waits on global.
// ---------------------------------------------------------------------------
__global__ __launch_bounds__(128) void nms_scan(
    const u64* __restrict__ M, const u64* __restrict__ Mdiag,
    const int* __restrict__ order,
    const int* __restrict__ svalid, float* __restrict__ outKeep) {
  __shared__ __align__(16) u64 sMdiag[8000];   // 64 KB: 125 tiles x 64 rows
  __shared__ u64 acc[126];
  __shared__ unsigned char klist[64];
  __shared__ int kcount;
  __shared__ int tv[125];
  __shared__ int nvt_s;
  const int tid = threadIdx.x;
  for (int i = tid; i < 4000; i += 128)
    ((float4*)sMdiag)[i] = ((const float4*)Mdiag)[i];
  for (int w = tid; w < 125; w += 128) acc[w] = 0;
  if (tid < 125) tv[tid] = svalid[tid * 64];
  __syncthreads();
  if (tid == 0) {
    int c = 0;
    while (c < 125 && tv[c]) ++c;
    nvt_s = c;
  }
  __syncthreads();
  const int nvt = nvt_s;

  for (int t = 0; t < nvt; ++t) {
    if (tid < 64) {  // wave 0: uniform scalar closure via readlane
      u64 myrow = sMdiag[t * 64 + tid];
      unsigned mlo = (unsigned)myrow, mhi = (unsigned)(myrow >> 32);
      u64 r = acc[t];
      for (int i = 0; i < 64; ++i) {
        u64 take = ((r >> i) & 1ULL) - 1ULL;    // all-ones iff bit i clear
        unsigned rlo = (unsigned)__builtin_amdgcn_readlane((int)mlo, i);
        unsigned rhi = (unsigned)__builtin_amdgcn_readlane((int)mhi, i);
        r |= (((u64)rhi << 32) | (u64)rlo) & take;
      }
      u64 kept = ~r;
      if (tid == 0) { acc[t] = r; kcount = (int)__popcll(kept); }
      if ((kept >> tid) & 1ULL)
        klist[__popcll(kept & ((1ULL << tid) - 1ULL))] = (unsigned char)tid;
    }
    __syncthreads();
    const int kc = kcount;
    const int w = t + 1 + tid;
    if (w < nvt) {
      u64 a = acc[w];
      const u64* base = M + (size_t)t * 64 * 128 + w;
      int j = 0;
      for (; j + 16 <= kc; j += 16) {   // 16 outstanding loads
        u64 o = 0;
#pragma unroll
        for (int q = 0; q < 16; ++q) o |= base[(size_t)klist[j + q] * 128];
        a |= o;
      }
      for (; j + 4 <= kc; j += 4) {
        u64 v0 = base[(size_t)klist[j] * 128];
        u64 v1 = base[(size_t)klist[j + 1] * 128];
        u64 v2 = base[(size_t)klist[j + 2] * 128];
        u64 v3 = base[(size_t)klist[j + 3] * 128];
        a |= (v0 | v1) | (v2 | v3);
      }
      for (; j < kc; ++j) a |= base[(size_t)klist[j] * 128];
      acc[w] = a;
    }
    __syncthreads();
  }

  for (int p = tid; p < 8000; p += 128) {
    int removed = (int)((acc[p >> 6] >> (p & 63)) & 1ULL);
    float kv = (!removed && svalid[p]) ? 1.0f : 0.0f;
    outKeep[order[p]] = kv;
  }
}

// ---------------------------------------------------------------------------
extern "C" void kernel_launch(void* const* d_in, const int* in_sizes, int n_in,
                              void* d_out, int out_size, void* d_ws, size_t ws_size,
                              hipStream_t stream) {
  const float* F    = (const float*)d_in[0];
  const float* ROIS = (const float*)d_in[1];
  const float* W6   = (const float*)d_in[2];
  const float* B6   = (const float*)d_in[3];
  const float* W7   = (const float*)d_in[4];
  const float* B7   = (const float*)d_in[5];
  const float* WC   = (const float*)d_in[6];
  const float* BC   = (const float*)d_in[7];
  const float* WR   = (const float*)d_in[8];
  const float* BR   = (const float*)d_in[9];

  const size_t N = 8000, D = 12544, H = 1024;
  char* ws = (char*)d_ws;
  size_t off = 0;
  auto alloc = [&](size_t bytes) -> void* {
    void* p = (void*)(ws + off);
    off += (bytes + 255) & ~(size_t)255;
    return p;
  };
  f16*   B1w   = (f16*)alloc(H * D * 2);
  f16*   B2w   = (f16*)alloc(H * D * 2);
  f16*   V61   = (f16*)alloc(N * H * 2);
  f16*   V62   = (f16*)alloc(N * H * 2);
  f16*   W71   = (f16*)alloc(H * H * 2);
  f16*   W72   = (f16*)alloc(H * H * 2);
  float* V7    = (float*)alloc(N * H * 4);
  float* SMASK = (float*)alloc(N * 4);
  float* WSBOX = (float*)alloc(N * 16);
  int*   WSVAL = (int*)alloc(N * 4);
  int*   ORDER = (int*)alloc(N * 4);
  float* SBOX  = (float*)alloc(N * 16);
  int*   SVAL  = (int*)alloc(N * 4);
  u64*   MM    = (u64*)alloc(N * 128 * 8);
  u64*   MDIAG = (u64*)alloc(125 * 64 * 8);

  float* outScores  = (float*)d_out;
  float* outClasses = (float*)d_out + 8000;
  float* outBoxes   = (float*)d_out + 16000;
  float* outKeep    = (float*)d_out + 48000;

  split_kernel<<<1024, 256, 0, stream>>>(W6, B1w, B2w, (long)(H * D / 4), 256.0f);
  split_kernel<<<256, 256, 0, stream>>>(W7, W71, W72, (long)(H * H / 4), 256.0f);

  gemm_split<1, 1><<<dim3(8, 32), 512, 0, stream>>>(F, nullptr, B1w, B2w, B6, V61, V62, 8000, 12544);
  gemm_split<2, 0><<<dim3(8, 32), 512, 0, stream>>>(V61, V62, W71, W72, B7, V7, nullptr, 8000, 1024);

  head_final<<<2000, 256, 0, stream>>>(V7, WC, BC, WR, BR, ROIS,
                                       outScores, outClasses, outBoxes,
                                       SMASK, WSBOX, WSVAL);
  rank_kernel<<<32, 256, 0, stream>>>(SMASK, WSBOX, WSVAL, ORDER, SBOX, SVAL);
  iou_matrix<<<dim3(125, 125), 64, 0, stream>>>(SBOX, MM, MDIAG, SVAL);
  nms_scan<<<1, 128, 0, stream>>>(MM, MDIAG, ORDER, SVAL, outKeep);
}

// Round 9
// 1375.516 us; speedup vs baseline: 1.0831x; 1.0235x over previous
//
#include <hip/hip_runtime.h>
#include <hip/hip_fp16.h>
#include <math.h>

typedef _Float16 f16;
typedef _Float16 f16x4 __attribute__((ext_vector_type(4)));
typedef _Float16 f16x8 __attribute__((ext_vector_type(8)));
typedef float f32x4 __attribute__((ext_vector_type(4)));
typedef unsigned long long u64;

// async global->LDS, 16B per lane; LDS dest must be wave-uniform base (HW adds lane*16)
#define GLD16(g, s) __builtin_amdgcn_global_load_lds( \
    (const __attribute__((address_space(1))) void*)(g), \
    (__attribute__((address_space(3))) void*)(s), 16, 0, 0)

// trunc+RNE split: hi = f16(x with mantissa truncated to 13 bits) [exact cast
// in normal range], lo = RNE residual. Measured absmax ~1e-3..4e-3.
struct HL { f16 h, l; };
__device__ __forceinline__ HL split1(float e) {
  float em = __uint_as_float(__float_as_uint(e) & 0xFFFFE000u);
  f16 hh = (f16)em;
  HL r;
  r.h = hh;
  r.l = (f16)(e - (float)hh);
  return r;
}

// ---------------------------------------------------------------------------
// split fp32 -> (hi, lo) f16 pair, pre-scaled by `scale` (=256). Weights only
// (F's split is fused into gemm_split<1,1>).
// ---------------------------------------------------------------------------
__global__ __launch_bounds__(256) void split_kernel(const float* __restrict__ src,
                                                    f16* __restrict__ hi,
                                                    f16* __restrict__ lo,
                                                    long n4, float scale) {
  long stride = (long)gridDim.x * blockDim.x;
  for (long i = (long)blockIdx.x * blockDim.x + threadIdx.x; i < n4; i += stride) {
    float4 v = ((const float4*)src)[i];
    f16x4 h, l;
    HL r0 = split1(v.x * scale); h[0] = r0.h; l[0] = r0.l;
    HL r1 = split1(v.y * scale); h[1] = r1.h; l[1] = r1.l;
    HL r2 = split1(v.z * scale); h[2] = r2.h; l[2] = r2.l;
    HL r3 = split1(v.w * scale); h[3] = r3.h; l[3] = r3.l;
    ((f16x4*)hi)[i] = h;
    ((f16x4*)lo)[i] = l;
  }
}

// ---------------------------------------------------------------------------
// Split-precision GEMM, 3-product (hi*hi + lo*hi + hi*lo), 16x16x32 MFMA.
// 256x128 tile, BK=32, 8 waves (4x2), triple-buffered LDS (144 KB),
// depth-2 prefetch, counted vmcnt(6). r4-proven loop schedule: frag loads/cvt
// FIRST, then STAGE prefetch, then MFMA block (no setprio — lockstep waves).
// AFP32=1: A staged raw fp32 (chunk-XOR c^(row&7)), hi/lo split in registers.
// AFP32=0: A pre-split f16 hi/lo (r7 zero-conflict pattern).
// ---------------------------------------------------------------------------
template<int EPI, int AFP32>
__global__ __launch_bounds__(512) void gemm_split(
    const void* __restrict__ Av1, const void* __restrict__ Av2,
    const f16* __restrict__ B1, const f16* __restrict__ B2,
    const float* __restrict__ bias,
    void* __restrict__ out1, void* __restrict__ out2,
    const int M, const int K) {
  // per buffer: A 32 KB (fp32 256x32 OR f16 hi+lo) | B1 8 KB | B2 8 KB = 48 KB
  __shared__ __align__(16) char smem[3][49152];
  const int tid = threadIdx.x;           // 0..511
  const int lane = tid & 63;
  const int wid = tid >> 6;              // 0..7
  const int wr = wid >> 1, wcol = wid & 1;
  const int m0 = blockIdx.y * 256;
  const int n0 = blockIdx.x * 128;

  f32x4 acc[4][4];
#pragma unroll
  for (int m = 0; m < 4; ++m)
#pragma unroll
    for (int n = 0; n < 4; ++n) acc[m][n] = (f32x4){0.f, 0.f, 0.f, 0.f};

  // ---- B staging (f16, r7 pattern, 0 conflicts) ----
  const int cg = (((tid & 3) ^ ((tid >> 3) & 3)) * 8);
  const f16* gB1 = B1 + (size_t)(n0 + (tid >> 2)) * K + cg;   // 128 rows
  const f16* gB2 = B2 + (size_t)(n0 + (tid >> 2)) * K + cg;

  // ---- A staging ----
  const float* gAf[4];                   // AFP32: fp32 256x32, chunk c^(row&7)
  if (AFP32) {
    const float* Af = (const float*)Av1;
#pragma unroll
    for (int q = 0; q < 4; ++q) {
      int rowg = m0 + q * 64 + (tid >> 3);
      if (rowg > M - 1) rowg = M - 1;
      const int chunkg = (tid & 7) ^ ((tid >> 3) & 7);
      gAf[q] = Af + (size_t)rowg * K + chunkg * 4;
    }
  }
  const f16 *gA1q0 = nullptr, *gA1q1 = nullptr, *gA2q0 = nullptr, *gA2q1 = nullptr;
  if (!AFP32) {
    int ra0 = m0 + (tid >> 2);       if (ra0 > M - 1) ra0 = M - 1;
    int ra1 = m0 + 128 + (tid >> 2); if (ra1 > M - 1) ra1 = M - 1;
    gA1q0 = (const f16*)Av1 + (size_t)ra0 * K + cg;
    gA1q1 = (const f16*)Av1 + (size_t)ra1 * K + cg;
    gA2q0 = (const f16*)Av2 + (size_t)ra0 * K + cg;
    gA2q1 = (const f16*)Av2 + (size_t)ra1 * K + cg;
  }

  const int arow = wr * 64 + (lane & 15);                    // + m*16 (swz m-indep)
  const int brow = wcol * 64 + (lane & 15);                  // + n*16
  const int kcA = (((lane >> 4) ^ ((arow >> 1) & 3)) * 8);   // f16-A read (0-conflict)
  const int kcB = (((lane >> 4) ^ ((brow >> 1) & 3)) * 8);
  const int pA0 = (((lane >> 4) * 2)     ^ (arow & 7)) * 4;  // fp32-A read (r3)
  const int pA1 = (((lane >> 4) * 2 + 1) ^ (arow & 7)) * 4;

  const int nt = K / 32;

#define STAGE(buf, kt)                                            \
  do {                                                            \
    char* smx_ = smem[buf];                                       \
    if (AFP32) {                                                  \
      float* db = (float*)smx_;                                   \
      GLD16(gAf[0] + (kt), db + 0 * 2048 + wid * 256);            \
      GLD16(gAf[1] + (kt), db + 1 * 2048 + wid * 256);            \
      GLD16(gAf[2] + (kt), db + 2 * 2048 + wid * 256);            \
      GLD16(gAf[3] + (kt), db + 3 * 2048 + wid * 256);            \
    } else {                                                      \
      f16* d1 = (f16*)smx_;                                       \
      f16* d2 = d1 + 8192;                                        \
      GLD16(gA1q0 + (kt), d1 + wid * 512);                        \
      GLD16(gA1q1 + (kt), d1 + 4096 + wid * 512);                 \
      GLD16(gA2q0 + (kt), d2 + wid * 512);                        \
      GLD16(gA2q1 + (kt), d2 + 4096 + wid * 512);                 \
    }                                                             \
    GLD16(gB1 + (kt), (f16*)(smx_ + 32768) + wid * 512);          \
    GLD16(gB2 + (kt), (f16*)(smx_ + 40960) + wid * 512);          \
  } while (0)
  // both variants = 6 GLD16/thread.

  STAGE(0, 0);
  if (nt > 1) STAGE(1, 32);
  int cur = 0;

  for (int t = 0; t < nt; ++t) {
    // own STAGE(t) drained (6 = STAGE(t+1) in flight); barrier extends the
    // guarantee across waves. Never drains to 0 mid-loop (T4).
    if (t + 1 < nt) asm volatile("s_waitcnt vmcnt(6)" ::: "memory");
    else            asm volatile("s_waitcnt vmcnt(0)" ::: "memory");
    asm volatile("s_waitcnt lgkmcnt(0)" ::: "memory");
    __builtin_amdgcn_s_barrier();
    __builtin_amdgcn_sched_barrier(0);

    const char* smx = smem[cur];
    f16x8 a1[4], a2[4], b1[4], b2[4];
    if (AFP32) {
      const float* sf = (const float*)smx;
#pragma unroll
      for (int m = 0; m < 4; ++m) {
        const float* rp = sf + (arow + m * 16) * 32;
        f32x4 u = *(const f32x4*)(rp + pA0);   // logical cols 8k..8k+3
        f32x4 v = *(const f32x4*)(rp + pA1);   // logical cols 8k+4..8k+7
        f16x8 h, l;
#pragma unroll
        for (int j = 0; j < 4; ++j) { HL r = split1(u[j] * 256.0f); h[j] = r.h; l[j] = r.l; }
#pragma unroll
        for (int j = 0; j < 4; ++j) { HL r = split1(v[j] * 256.0f); h[4 + j] = r.h; l[4 + j] = r.l; }
        a1[m] = h; a2[m] = l;
      }
    } else {
      const f16* s1 = (const f16*)smx;
      const f16* s2 = s1 + 8192;
#pragma unroll
      for (int m = 0; m < 4; ++m) {
        a1[m] = *(const f16x8*)&s1[(arow + m * 16) * 32 + kcA];
        a2[m] = *(const f16x8*)&s2[(arow + m * 16) * 32 + kcA];
      }
    }
    {
      const f16* sb1 = (const f16*)(smx + 32768);
      const f16* sb2 = (const f16*)(smx + 40960);
#pragma unroll
      for (int n = 0; n < 4; ++n) {
        b1[n] = *(const f16x8*)&sb1[(brow + n * 16) * 32 + kcB];
        b2[n] = *(const f16x8*)&sb2[(brow + n * 16) * 32 + kcB];
      }
    }

    int pre = cur + 2; if (pre >= 3) pre -= 3;
    if (t + 2 < nt) STAGE(pre, (t + 2) * 32);   // r4 placement: after reads

#pragma unroll
    for (int m = 0; m < 4; ++m)
#pragma unroll
      for (int n = 0; n < 4; ++n) {
        acc[m][n] = __builtin_amdgcn_mfma_f32_16x16x32_f16(a1[m], b1[n], acc[m][n], 0, 0, 0);
        acc[m][n] = __builtin_amdgcn_mfma_f32_16x16x32_f16(a2[m], b1[n], acc[m][n], 0, 0, 0);
        acc[m][n] = __builtin_amdgcn_mfma_f32_16x16x32_f16(a1[m], b2[n], acc[m][n], 0, 0, 0);
      }
    ++cur; if (cur >= 3) cur = 0;
  }
#undef STAGE

  // epilogue: D mapping col=lane&15, row=4*(lane>>4)+j (m89-verified)
  const int crow = m0 + wr * 64 + 4 * (lane >> 4);
  const int ccol0 = n0 + wcol * 64 + (lane & 15);
#pragma unroll
  for (int n = 0; n < 4; ++n) {
    const int col = ccol0 + n * 16;
    const float bv = bias[col];
#pragma unroll
    for (int m = 0; m < 4; ++m) {
#pragma unroll
      for (int j = 0; j < 4; ++j) {
        const int row = crow + m * 16 + j;
        if (row < M) {
          float v = acc[m][n][j] * (1.0f / 65536.0f) + bv;
          v = fmaxf(v, 0.0f);
          if (EPI == 1) {
            HL r = split1(v * 256.0f);
            ((f16*)out1)[(size_t)row * 1024 + col] = r.h;
            ((f16*)out2)[(size_t)row * 1024 + col] = r.l;
          } else {
            ((float*)out1)[(size_t)row * 1024 + col] = v;
          }
        }
      }
    }
  }
}

// ---------------------------------------------------------------------------
// Final head: c/r dots (fp32), argmax/scores, per-class delta, box decode+clip
// ---------------------------------------------------------------------------
__device__ __forceinline__ float dot4f(float4 a, float4 b) {
  return a.x * b.x + a.y * b.y + a.z * b.z + a.w * b.w;
}

__global__ __launch_bounds__(256) void head_final(
    const float* __restrict__ v7,
    const float* __restrict__ wc, const float* __restrict__ bc,
    const float* __restrict__ wr, const float* __restrict__ br,
    const float* __restrict__ rois,
    float* __restrict__ outScores, float* __restrict__ outClasses,
    float* __restrict__ outBoxes,
    float* __restrict__ smask, float* __restrict__ wsbox, int* __restrict__ wsval) {
  const int gw = (blockIdx.x * 256 + threadIdx.x) >> 6;
  const int lane = threadIdx.x & 63;
  if (gw >= 8000) return;

  const float4* vr = (const float4*)(v7 + (size_t)gw * 1024);
  float4 x0 = vr[lane], x1 = vr[64 + lane], x2 = vr[128 + lane], x3 = vr[192 + lane];

  float s[20];
#pragma unroll
  for (int o = 0; o < 20; ++o) {
    const float* wrow = (o < 4) ? (wc + o * 1024) : (wr + (o - 4) * 1024);
    const float4* w4 = (const float4*)wrow;
    float a = dot4f(x0, w4[lane]) + dot4f(x1, w4[64 + lane]) +
              dot4f(x2, w4[128 + lane]) + dot4f(x3, w4[192 + lane]);
#pragma unroll
    for (int off = 32; off >= 1; off >>= 1) a += __shfl_xor(a, off);
    s[o] = a + ((o < 4) ? bc[o] : br[o - 4]);
  }

  float best = s[0]; int cls = 0;
  if (s[1] > best) { best = s[1]; cls = 1; }
  if (s[2] > best) { best = s[2]; cls = 2; }
  if (s[3] > best) { best = s[3]; cls = 3; }

  float d0, d1, d2, d3;  // constant indices only (avoid scratch)
  if      (cls == 0) { d0 = s[4];  d1 = s[5];  d2 = s[6];  d3 = s[7];  }
  else if (cls == 1) { d0 = s[8];  d1 = s[9];  d2 = s[10]; d3 = s[11]; }
  else if (cls == 2) { d0 = s[12]; d1 = s[13]; d2 = s[14]; d3 = s[15]; }
  else               { d0 = s[16]; d1 = s[17]; d2 = s[18]; d3 = s[19]; }

  float4 rb = ((const float4*)rois)[gw];
  float w = rb.z - rb.x, h = rb.w - rb.y;
  float cx = rb.x + 0.5f * w, cy = rb.y + 0.5f * h;
  float pcx = cx + d0 * 0.1f * w;
  float pcy = cy + d1 * 0.1f * h;
  float pw = expf(d2 * 0.2f) * w;
  float ph = expf(d3 * 0.2f) * h;
  float bx0 = fminf(fmaxf(pcx - 0.5f * pw, 0.f), 512.f);
  float by0 = fminf(fmaxf(pcy - 0.5f * ph, 0.f), 512.f);
  float bx1 = fminf(fmaxf(pcx + 0.5f * pw, 0.f), 512.f);
  float by1 = fminf(fmaxf(pcy + 0.5f * ph, 0.f), 512.f);

  if (lane == 0) {
    outScores[gw] = best;
    outClasses[gw] = (float)cls;
    outBoxes[gw * 4 + 0] = bx0;
    outBoxes[gw * 4 + 1] = by0;
    outBoxes[gw * 4 + 2] = bx1;
    outBoxes[gw * 4 + 3] = by1;
    int valid = (cls != 3);
    smask[gw] = valid ? best : -INFINITY;
    wsval[gw] = valid;
    float4 bb; bb.x = bx0; bb.y = by0; bb.z = bx1; bb.w = by1;
    ((float4*)wsbox)[gw] = bb;
  }
}

// ---------------------------------------------------------------------------
// Stable descending rank (== argsort(-s) position), then scatter to sorted arrays
// ---------------------------------------------------------------------------
__global__ __launch_bounds__(256) void rank_kernel(
    const float* __restrict__ smask, const float* __restrict__ bx,
    const int* __restrict__ valid,
    int* __restrict__ order, float* __restrict__ sboxes, int* __restrict__ svalid) {
  __shared__ __align__(16) float sS[8000];
  const int tid = threadIdx.x;
  for (int i = tid; i < 8000; i += 256) sS[i] = smask[i];
  __syncthreads();
  const int i = blockIdx.x * 256 + tid;
  if (i >= 8000) return;
  const float si = sS[i];
  int cnt = 0;
  const float4* s4p = (const float4*)sS;
  for (int j4 = 0; j4 < 2000; ++j4) {
    float4 s4 = s4p[j4];
    int jb = j4 * 4;
    cnt += (s4.x > si) || (s4.x == si && (jb + 0) < i);
    cnt += (s4.y > si) || (s4.y == si && (jb + 1) < i);
    cnt += (s4.z > si) || (s4.z == si && (jb + 2) < i);
    cnt += (s4.w > si) || (s4.w == si && (jb + 3) < i);
  }
  order[cnt] = i;
  svalid[cnt] = valid[i];
  ((float4*)sboxes)[cnt] = ((const float4*)bx)[i];
}

// ---------------------------------------------------------------------------
// Suppression bitmask matrix in SORTED order; skips all-invalid tile pairs
// (same predicate as nms_scan, so no poisoned M word is ever read).
// ---------------------------------------------------------------------------
__global__ void iou_matrix(const float* __restrict__ sboxes, u64* __restrict__ M,
                           u64* __restrict__ Mdiag, const int* __restrict__ svalid) {
  const int t = blockIdx.y, w = blockIdx.x;
  if (w < t) return;
  if (svalid[t * 64] == 0 || svalid[w * 64] == 0) return;
  const int lane = threadIdx.x;
  __shared__ __align__(16) float cb[64 * 4];
  ((float4*)cb)[lane] = ((const float4*)sboxes)[w * 64 + lane];
  __syncthreads();
  const int ri = t * 64 + lane;
  float4 rb = ((const float4*)sboxes)[ri];
  const float ra = (rb.z - rb.x) * (rb.w - rb.y);
  u64 bits = 0;
  for (int j = 0; j < 64; ++j) {
    float4 c = ((float4*)cb)[j];
    float x1 = fmaxf(rb.x, c.x), y1 = fmaxf(rb.y, c.y);
    float x2 = fminf(rb.z, c.z), y2 = fminf(rb.w, c.w);
    float inter = fmaxf(x2 - x1, 0.f) * fmaxf(y2 - y1, 0.f);
    float ca = (c.z - c.x) * (c.w - c.y);
    float iou = inter / (ra + ca - inter + 1e-8f);
    int gc = w * 64 + j;
    if (iou > 0.2f && gc > ri) bits |= (1ULL << j);
  }
  M[(size_t)ri * 128 + w] = bits;
  if (w == t) Mdiag[(size_t)t * 64 + lane] = bits;
}

// ---------------------------------------------------------------------------
// Sequential greedy NMS scan, truncated to valid tiles. Mdiag staged fully
// in LDS upfront (64 KB) so the serial closure chain never waits on global.
// ---------------------------------------------------------------------------
__global__ __launch_bounds__(128) void nms_scan(
    const u64* __restrict__ M, const u64* __restrict__ Mdiag,
    const int* __restrict__ order,
    const int* __restrict__ svalid, float* __restrict__ outKeep) {
  __shared__ __align__(16) u64 sMdiag[8000];   // 64 KB: 125 tiles x 64 rows
  __shared__ u64 acc[126];
  __shared__ unsigned char klist[64];
  __shared__ int kcount;
  __shared__ int tv[125];
  __shared__ int nvt_s;
  const int tid = threadIdx.x;
  for (int i = tid; i < 4000; i += 128)
    ((float4*)sMdiag)[i] = ((const float4*)Mdiag)[i];
  for (int w = tid; w < 125; w += 128) acc[w] = 0;
  if (tid < 125) tv[tid] = svalid[tid * 64];
  __syncthreads();
  if (tid == 0) {
    int c = 0;
    while (c < 125 && tv[c]) ++c;
    nvt_s = c;
  }
  __syncthreads();
  const int nvt = nvt_s;

  for (int t = 0; t < nvt; ++t) {
    if (tid < 64) {  // wave 0: uniform scalar closure via readlane
      u64 myrow = sMdiag[t * 64 + tid];
      unsigned mlo = (unsigned)myrow, mhi = (unsigned)(myrow >> 32);
      u64 r = acc[t];
      for (int i = 0; i < 64; ++i) {
        u64 take = ((r >> i) & 1ULL) - 1ULL;    // all-ones iff bit i clear
        unsigned rlo = (unsigned)__builtin_amdgcn_readlane((int)mlo, i);
        unsigned rhi = (unsigned)__builtin_amdgcn_readlane((int)mhi, i);
        r |= (((u64)rhi << 32) | (u64)rlo) & take;
      }
      u64 kept = ~r;
      if (tid == 0) { acc[t] = r; kcount = (int)__popcll(kept); }
      if ((kept >> tid) & 1ULL)
        klist[__popcll(kept & ((1ULL << tid) - 1ULL))] = (unsigned char)tid;
    }
    __syncthreads();
    const int kc = kcount;
    const int w = t + 1 + tid;
    if (w < nvt) {
      u64 a = acc[w];
      const u64* base = M + (size_t)t * 64 * 128 + w;
      int j = 0;
      for (; j + 16 <= kc; j += 16) {   // 16 outstanding loads
        u64 o = 0;
#pragma unroll
        for (int q = 0; q < 16; ++q) o |= base[(size_t)klist[j + q] * 128];
        a |= o;
      }
      for (; j + 4 <= kc; j += 4) {
        u64 v0 = base[(size_t)klist[j] * 128];
        u64 v1 = base[(size_t)klist[j + 1] * 128];
        u64 v2 = base[(size_t)klist[j + 2] * 128];
        u64 v3 = base[(size_t)klist[j + 3] * 128];
        a |= (v0 | v1) | (v2 | v3);
      }
      for (; j < kc; ++j) a |= base[(size_t)klist[j] * 128];
      acc[w] = a;
    }
    __syncthreads();
  }

  for (int p = tid; p < 8000; p += 128) {
    int removed = (int)((acc[p >> 6] >> (p & 63)) & 1ULL);
    float kv = (!removed && svalid[p]) ? 1.0f : 0.0f;
    outKeep[order[p]] = kv;
  }
}

// ---------------------------------------------------------------------------
extern "C" void kernel_launch(void* const* d_in, const int* in_sizes, int n_in,
                              void* d_out, int out_size, void* d_ws, size_t ws_size,
                              hipStream_t stream) {
  const float* F    = (const float*)d_in[0];
  const float* ROIS = (const float*)d_in[1];
  const float* W6   = (const float*)d_in[2];
  const float* B6   = (const float*)d_in[3];
  const float* W7   = (const float*)d_in[4];
  const float* B7   = (const float*)d_in[5];
  const float* WC   = (const float*)d_in[6];
  const float* BC   = (const float*)d_in[7];
  const float* WR   = (const float*)d_in[8];
  const float* BR   = (const float*)d_in[9];

  const size_t N = 8000, D = 12544, H = 1024;
  char* ws = (char*)d_ws;
  size_t off = 0;
  auto alloc = [&](size_t bytes) -> void* {
    void* p = (void*)(ws + off);
    off += (bytes + 255) & ~(size_t)255;
    return p;
  };
  f16*   B1w   = (f16*)alloc(H * D * 2);
  f16*   B2w   = (f16*)alloc(H * D * 2);
  f16*   V61   = (f16*)alloc(N * H * 2);
  f16*   V62   = (f16*)alloc(N * H * 2);
  f16*   W71   = (f16*)alloc(H * H * 2);
  f16*   W72   = (f16*)alloc(H * H * 2);
  float* V7    = (float*)alloc(N * H * 4);
  float* SMASK = (float*)alloc(N * 4);
  float* WSBOX = (float*)alloc(N * 16);
  int*   WSVAL = (int*)alloc(N * 4);
  int*   ORDER = (int*)alloc(N * 4);
  float* SBOX  = (float*)alloc(N * 16);
  int*   SVAL  = (int*)alloc(N * 4);
  u64*   MM    = (u64*)alloc(N * 128 * 8);
  u64*   MDIAG = (u64*)alloc(125 * 64 * 8);

  float* outScores  = (float*)d_out;
  float* outClasses = (float*)d_out + 8000;
  float* outBoxes   = (float*)d_out + 16000;
  float* outKeep    = (float*)d_out + 48000;

  split_kernel<<<1024, 256, 0, stream>>>(W6, B1w, B2w, (long)(H * D / 4), 256.0f);
  split_kernel<<<256, 256, 0, stream>>>(W7, W71, W72, (long)(H * H / 4), 256.0f);

  gemm_split<1, 1><<<dim3(8, 32), 512, 0, stream>>>(F, nullptr, B1w, B2w, B6, V61, V62, 8000, 12544);
  gemm_split<2, 0><<<dim3(8, 32), 512, 0, stream>>>(V61, V62, W71, W72, B7, V7, nullptr, 8000, 1024);

  head_final<<<2000, 256, 0, stream>>>(V7, WC, BC, WR, BR, ROIS,
                                       outScores, outClasses, outBoxes,
                                       SMASK, WSBOX, WSVAL);
  rank_kernel<<<32, 256, 0, stream>>>(SMASK, WSBOX, WSVAL, ORDER, SBOX, SVAL);
  iou_matrix<<<dim3(125, 125), 64, 0, stream>>>(SBOX, MM, MDIAG, SVAL);
  nms_scan<<<1, 128, 0, stream>>>(MM, MDIAG, ORDER, SVAL, outKeep);
}

// Round 10
// 1369.061 us; speedup vs baseline: 1.0882x; 1.0047x over previous
//
#include <hip/hip_runtime.h>
#include <hip/hip_fp16.h>
#include <math.h>

typedef _Float16 f16;
typedef _Float16 f16x4 __attribute__((ext_vector_type(4)));
typedef _Float16 f16x8 __attribute__((ext_vector_type(8)));
typedef float f32x4 __attribute__((ext_vector_type(4)));
typedef unsigned long long u64;

// async global->LDS, 16B per lane; LDS dest must be wave-uniform base (HW adds lane*16)
#define GLD16(g, s) __builtin_amdgcn_global_load_lds( \
    (const __attribute__((address_space(1))) void*)(g), \
    (__attribute__((address_space(3))) void*)(s), 16, 0, 0)

// trunc+RNE split: hi = f16(x mantissa-truncated to 13 bits) [exact cast in
// range], lo = RNE(e - em). (float)hi == em exactly, so subtract em directly
// (saves a cvt on the dependent chain; bit-identical to r9). absmax ~4e-3.
struct HL { f16 h, l; };
__device__ __forceinline__ HL split1(float e) {
  float em = __uint_as_float(__float_as_uint(e) & 0xFFFFE000u);
  HL r;
  r.h = (f16)em;
  r.l = (f16)(e - em);
  return r;
}

// ---------------------------------------------------------------------------
// split fp32 -> (hi, lo) f16 pair, pre-scaled by `scale` (=256). Weights only
// (F's split is fused into gemm_split<1,1>).
// ---------------------------------------------------------------------------
__global__ __launch_bounds__(256) void split_kernel(const float* __restrict__ src,
                                                    f16* __restrict__ hi,
                                                    f16* __restrict__ lo,
                                                    long n4, float scale) {
  long stride = (long)gridDim.x * blockDim.x;
  for (long i = (long)blockIdx.x * blockDim.x + threadIdx.x; i < n4; i += stride) {
    float4 v = ((const float4*)src)[i];
    f16x4 h, l;
    HL r0 = split1(v.x * scale); h[0] = r0.h; l[0] = r0.l;
    HL r1 = split1(v.y * scale); h[1] = r1.h; l[1] = r1.l;
    HL r2 = split1(v.z * scale); h[2] = r2.h; l[2] = r2.l;
    HL r3 = split1(v.w * scale); h[3] = r3.h; l[3] = r3.l;
    ((f16x4*)hi)[i] = h;
    ((f16x4*)lo)[i] = l;
  }
}

// ---------------------------------------------------------------------------
// Split-precision GEMM, 3-product (hi*hi + lo*hi + hi*lo), 16x16x32 MFMA.
// 256x128 tile, BK=32, 8 waves (4x2), triple-buffered LDS (144 KB),
// depth-2 prefetch, counted vmcnt(6). r4-proven schedule: frag loads/cvt
// first, then STAGE prefetch, then MFMA (no setprio — lockstep waves).
// AFP32=1: A staged raw fp32 (chunk-XOR c^(row&7)), hi/lo split in registers.
// AFP32=0: A pre-split f16 hi/lo (r7 zero-conflict pattern).
// ---------------------------------------------------------------------------
template<int EPI, int AFP32>
__global__ __launch_bounds__(512) void gemm_split(
    const void* __restrict__ Av1, const void* __restrict__ Av2,
    const f16* __restrict__ B1, const f16* __restrict__ B2,
    const float* __restrict__ bias,
    void* __restrict__ out1, void* __restrict__ out2,
    const int M, const int K) {
  // per buffer: A 32 KB (fp32 256x32 OR f16 hi+lo) | B1 8 KB | B2 8 KB = 48 KB
  __shared__ __align__(16) char smem[3][49152];
  const int tid = threadIdx.x;           // 0..511
  const int lane = tid & 63;
  const int wid = tid >> 6;              // 0..7
  const int wr = wid >> 1, wcol = wid & 1;
  const int m0 = blockIdx.y * 256;
  const int n0 = blockIdx.x * 128;

  f32x4 acc[4][4];
#pragma unroll
  for (int m = 0; m < 4; ++m)
#pragma unroll
    for (int n = 0; n < 4; ++n) acc[m][n] = (f32x4){0.f, 0.f, 0.f, 0.f};

  // ---- B staging (f16, r7 pattern, 0 conflicts) ----
  const int cg = (((tid & 3) ^ ((tid >> 3) & 3)) * 8);
  const f16* gB1 = B1 + (size_t)(n0 + (tid >> 2)) * K + cg;   // 128 rows
  const f16* gB2 = B2 + (size_t)(n0 + (tid >> 2)) * K + cg;

  // ---- A staging ----
  const float* gAf[4];                   // AFP32: fp32 256x32, chunk c^(row&7)
  if (AFP32) {
    const float* Af = (const float*)Av1;
#pragma unroll
    for (int q = 0; q < 4; ++q) {
      int rowg = m0 + q * 64 + (tid >> 3);
      if (rowg > M - 1) rowg = M - 1;
      const int chunkg = (tid & 7) ^ ((tid >> 3) & 7);
      gAf[q] = Af + (size_t)rowg * K + chunkg * 4;
    }
  }
  const f16 *gA1q0 = nullptr, *gA1q1 = nullptr, *gA2q0 = nullptr, *gA2q1 = nullptr;
  if (!AFP32) {
    int ra0 = m0 + (tid >> 2);       if (ra0 > M - 1) ra0 = M - 1;
    int ra1 = m0 + 128 + (tid >> 2); if (ra1 > M - 1) ra1 = M - 1;
    gA1q0 = (const f16*)Av1 + (size_t)ra0 * K + cg;
    gA1q1 = (const f16*)Av1 + (size_t)ra1 * K + cg;
    gA2q0 = (const f16*)Av2 + (size_t)ra0 * K + cg;
    gA2q1 = (const f16*)Av2 + (size_t)ra1 * K + cg;
  }

  const int arow = wr * 64 + (lane & 15);                    // + m*16 (swz m-indep)
  const int brow = wcol * 64 + (lane & 15);                  // + n*16
  const int kcA = (((lane >> 4) ^ ((arow >> 1) & 3)) * 8);   // f16-A read (0-conflict)
  const int kcB = (((lane >> 4) ^ ((brow >> 1) & 3)) * 8);
  const int pA0 = (((lane >> 4) * 2)     ^ (arow & 7)) * 4;  // fp32-A read (r3)
  const int pA1 = (((lane >> 4) * 2 + 1) ^ (arow & 7)) * 4;

  const int nt = K / 32;

#define STAGE(buf, kt)                                            \
  do {                                                            \
    char* smx_ = smem[buf];                                       \
    if (AFP32) {                                                  \
      float* db = (float*)smx_;                                   \
      GLD16(gAf[0] + (kt), db + 0 * 2048 + wid * 256);            \
      GLD16(gAf[1] + (kt), db + 1 * 2048 + wid * 256);            \
      GLD16(gAf[2] + (kt), db + 2 * 2048 + wid * 256);            \
      GLD16(gAf[3] + (kt), db + 3 * 2048 + wid * 256);            \
    } else {                                                      \
      f16* d1 = (f16*)smx_;                                       \
      f16* d2 = d1 + 8192;                                        \
      GLD16(gA1q0 + (kt), d1 + wid * 512);                        \
      GLD16(gA1q1 + (kt), d1 + 4096 + wid * 512);                 \
      GLD16(gA2q0 + (kt), d2 + wid * 512);                        \
      GLD16(gA2q1 + (kt), d2 + 4096 + wid * 512);                 \
    }                                                             \
    GLD16(gB1 + (kt), (f16*)(smx_ + 32768) + wid * 512);          \
    GLD16(gB2 + (kt), (f16*)(smx_ + 40960) + wid * 512);          \
  } while (0)
  // both variants = 6 GLD16/thread.

  STAGE(0, 0);
  if (nt > 1) STAGE(1, 32);
  int cur = 0;

  for (int t = 0; t < nt; ++t) {
    // own STAGE(t) drained (6 = STAGE(t+1) in flight); barrier extends the
    // guarantee across waves. Never drains to 0 mid-loop (T4).
    if (t + 1 < nt) asm volatile("s_waitcnt vmcnt(6)" ::: "memory");
    else            asm volatile("s_waitcnt vmcnt(0)" ::: "memory");
    asm volatile("s_waitcnt lgkmcnt(0)" ::: "memory");
    __builtin_amdgcn_s_barrier();
    __builtin_amdgcn_sched_barrier(0);

    const char* smx = smem[cur];
    f16x8 a1[4], a2[4], b1[4], b2[4];
    if (AFP32) {
      const float* sf = (const float*)smx;
#pragma unroll
      for (int m = 0; m < 4; ++m) {
        const float* rp = sf + (arow + m * 16) * 32;
        f32x4 u = *(const f32x4*)(rp + pA0);   // logical cols 8k..8k+3
        f32x4 v = *(const f32x4*)(rp + pA1);   // logical cols 8k+4..8k+7
        f16x8 h, l;
#pragma unroll
        for (int j = 0; j < 4; ++j) { HL r = split1(u[j] * 256.0f); h[j] = r.h; l[j] = r.l; }
#pragma unroll
        for (int j = 0; j < 4; ++j) { HL r = split1(v[j] * 256.0f); h[4 + j] = r.h; l[4 + j] = r.l; }
        a1[m] = h; a2[m] = l;
      }
    } else {
      const f16* s1 = (const f16*)smx;
      const f16* s2 = s1 + 8192;
#pragma unroll
      for (int m = 0; m < 4; ++m) {
        a1[m] = *(const f16x8*)&s1[(arow + m * 16) * 32 + kcA];
        a2[m] = *(const f16x8*)&s2[(arow + m * 16) * 32 + kcA];
      }
    }
    {
      const f16* sb1 = (const f16*)(smx + 32768);
      const f16* sb2 = (const f16*)(smx + 40960);
#pragma unroll
      for (int n = 0; n < 4; ++n) {
        b1[n] = *(const f16x8*)&sb1[(brow + n * 16) * 32 + kcB];
        b2[n] = *(const f16x8*)&sb2[(brow + n * 16) * 32 + kcB];
      }
    }

    int pre = cur + 2; if (pre >= 3) pre -= 3;
    if (t + 2 < nt) STAGE(pre, (t + 2) * 32);   // r4 placement: after reads

#pragma unroll
    for (int m = 0; m < 4; ++m)
#pragma unroll
      for (int n = 0; n < 4; ++n) {
        acc[m][n] = __builtin_amdgcn_mfma_f32_16x16x32_f16(a1[m], b1[n], acc[m][n], 0, 0, 0);
        acc[m][n] = __builtin_amdgcn_mfma_f32_16x16x32_f16(a2[m], b1[n], acc[m][n], 0, 0, 0);
        acc[m][n] = __builtin_amdgcn_mfma_f32_16x16x32_f16(a1[m], b2[n], acc[m][n], 0, 0, 0);
      }
    ++cur; if (cur >= 3) cur = 0;
  }
#undef STAGE

  // epilogue: D mapping col=lane&15, row=4*(lane>>4)+j (m89-verified)
  const int crow = m0 + wr * 64 + 4 * (lane >> 4);
  const int ccol0 = n0 + wcol * 64 + (lane & 15);
#pragma unroll
  for (int n = 0; n < 4; ++n) {
    const int col = ccol0 + n * 16;
    const float bv = bias[col];
#pragma unroll
    for (int m = 0; m < 4; ++m) {
#pragma unroll
      for (int j = 0; j < 4; ++j) {
        const int row = crow + m * 16 + j;
        if (row < M) {
          float v = acc[m][n][j] * (1.0f / 65536.0f) + bv;
          v = fmaxf(v, 0.0f);
          if (EPI == 1) {
            HL r = split1(v * 256.0f);
            ((f16*)out1)[(size_t)row * 1024 + col] = r.h;
            ((f16*)out2)[(size_t)row * 1024 + col] = r.l;
          } else {
            ((float*)out1)[(size_t)row * 1024 + col] = v;
          }
        }
      }
    }
  }
}

// ---------------------------------------------------------------------------
// Final head: c/r dots (fp32), argmax/scores, per-class delta, box decode+clip
// ---------------------------------------------------------------------------
__device__ __forceinline__ float dot4f(float4 a, float4 b) {
  return a.x * b.x + a.y * b.y + a.z * b.z + a.w * b.w;
}

__global__ __launch_bounds__(256) void head_final(
    const float* __restrict__ v7,
    const float* __restrict__ wc, const float* __restrict__ bc,
    const float* __restrict__ wr, const float* __restrict__ br,
    const float* __restrict__ rois,
    float* __restrict__ outScores, float* __restrict__ outClasses,
    float* __restrict__ outBoxes,
    float* __restrict__ smask, float* __restrict__ wsbox, int* __restrict__ wsval) {
  const int gw = (blockIdx.x * 256 + threadIdx.x) >> 6;
  const int lane = threadIdx.x & 63;
  if (gw >= 8000) return;

  const float4* vr = (const float4*)(v7 + (size_t)gw * 1024);
  float4 x0 = vr[lane], x1 = vr[64 + lane], x2 = vr[128 + lane], x3 = vr[192 + lane];

  float s[20];
#pragma unroll
  for (int o = 0; o < 20; ++o) {
    const float* wrow = (o < 4) ? (wc + o * 1024) : (wr + (o - 4) * 1024);
    const float4* w4 = (const float4*)wrow;
    float a = dot4f(x0, w4[lane]) + dot4f(x1, w4[64 + lane]) +
              dot4f(x2, w4[128 + lane]) + dot4f(x3, w4[192 + lane]);
#pragma unroll
    for (int off = 32; off >= 1; off >>= 1) a += __shfl_xor(a, off);
    s[o] = a + ((o < 4) ? bc[o] : br[o - 4]);
  }

  float best = s[0]; int cls = 0;
  if (s[1] > best) { best = s[1]; cls = 1; }
  if (s[2] > best) { best = s[2]; cls = 2; }
  if (s[3] > best) { best = s[3]; cls = 3; }

  float d0, d1, d2, d3;  // constant indices only (avoid scratch)
  if      (cls == 0) { d0 = s[4];  d1 = s[5];  d2 = s[6];  d3 = s[7];  }
  else if (cls == 1) { d0 = s[8];  d1 = s[9];  d2 = s[10]; d3 = s[11]; }
  else if (cls == 2) { d0 = s[12]; d1 = s[13]; d2 = s[14]; d3 = s[15]; }
  else               { d0 = s[16]; d1 = s[17]; d2 = s[18]; d3 = s[19]; }

  float4 rb = ((const float4*)rois)[gw];
  float w = rb.z - rb.x, h = rb.w - rb.y;
  float cx = rb.x + 0.5f * w, cy = rb.y + 0.5f * h;
  float pcx = cx + d0 * 0.1f * w;
  float pcy = cy + d1 * 0.1f * h;
  float pw = expf(d2 * 0.2f) * w;
  float ph = expf(d3 * 0.2f) * h;
  float bx0 = fminf(fmaxf(pcx - 0.5f * pw, 0.f), 512.f);
  float by0 = fminf(fmaxf(pcy - 0.5f * ph, 0.f), 512.f);
  float bx1 = fminf(fmaxf(pcx + 0.5f * pw, 0.f), 512.f);
  float by1 = fminf(fmaxf(pcy + 0.5f * ph, 0.f), 512.f);

  if (lane == 0) {
    outScores[gw] = best;
    outClasses[gw] = (float)cls;
    outBoxes[gw * 4 + 0] = bx0;
    outBoxes[gw * 4 + 1] = by0;
    outBoxes[gw * 4 + 2] = bx1;
    outBoxes[gw * 4 + 3] = by1;
    int valid = (cls != 3);
    smask[gw] = valid ? best : -INFINITY;
    wsval[gw] = valid;
    float4 bb; bb.x = bx0; bb.y = by0; bb.z = bx1; bb.w = by1;
    ((float4*)wsbox)[gw] = bb;
  }
}

// ---------------------------------------------------------------------------
// Stable descending rank (== argsort(-s) position), then scatter to sorted arrays
// ---------------------------------------------------------------------------
__global__ __launch_bounds__(256) void rank_kernel(
    const float* __restrict__ smask, const float* __restrict__ bx,
    const int* __restrict__ valid,
    int* __restrict__ order, float* __restrict__ sboxes, int* __restrict__ svalid) {
  __shared__ __align__(16) float sS[8000];
  const int tid = threadIdx.x;
  for (int i = tid; i < 8000; i += 256) sS[i] = smask[i];
  __syncthreads();
  const int i = blockIdx.x * 256 + tid;
  if (i >= 8000) return;
  const float si = sS[i];
  int cnt = 0;
  const float4* s4p = (const float4*)sS;
  for (int j4 = 0; j4 < 2000; ++j4) {
    float4 s4 = s4p[j4];
    int jb = j4 * 4;
    cnt += (s4.x > si) || (s4.x == si && (jb + 0) < i);
    cnt += (s4.y > si) || (s4.y == si && (jb + 1) < i);
    cnt += (s4.z > si) || (s4.z == si && (jb + 2) < i);
    cnt += (s4.w > si) || (s4.w == si && (jb + 3) < i);
  }
  order[cnt] = i;
  svalid[cnt] = valid[i];
  ((float4*)sboxes)[cnt] = ((const float4*)bx)[i];
}

// ---------------------------------------------------------------------------
// Suppression bitmask matrix in SORTED order; one (t,w) tile-pair per WAVE,
// 4 waves/block -> 4,000 blocks instead of 15,625 (dispatch-overhead fix).
// c-boxes read via loop-uniform loads (L1-resident, 1 KB/tile) — no LDS,
// no barriers. Skips all-invalid pairs (same predicate as nms_scan).
// ---------------------------------------------------------------------------
__global__ __launch_bounds__(256) void iou_matrix(const float* __restrict__ sboxes,
                                                  u64* __restrict__ M,
                                                  u64* __restrict__ Mdiag,
                                                  const int* __restrict__ svalid) {
  const int t = blockIdx.y;
  const int w = blockIdx.x * 4 + (threadIdx.x >> 6);
  if (w < t || w >= 125) return;
  if (svalid[t * 64] == 0 || svalid[w * 64] == 0) return;
  const int lane = threadIdx.x & 63;
  const int ri = t * 64 + lane;
  float4 rb = ((const float4*)sboxes)[ri];
  const float ra = (rb.z - rb.x) * (rb.w - rb.y);
  const float4* cb = (const float4*)sboxes + w * 64;
  u64 bits = 0;
#pragma unroll 4
  for (int j = 0; j < 64; ++j) {
    float4 c = cb[j];
    float x1 = fmaxf(rb.x, c.x), y1 = fmaxf(rb.y, c.y);
    float x2 = fminf(rb.z, c.z), y2 = fminf(rb.w, c.w);
    float inter = fmaxf(x2 - x1, 0.f) * fmaxf(y2 - y1, 0.f);
    float ca = (c.z - c.x) * (c.w - c.y);
    float iou = inter / (ra + ca - inter + 1e-8f);
    int gc = w * 64 + j;
    if (iou > 0.2f && gc > ri) bits |= (1ULL << j);
  }
  M[(size_t)ri * 128 + w] = bits;
  if (w == t) Mdiag[(size_t)t * 64 + lane] = bits;
}

// ---------------------------------------------------------------------------
// Sequential greedy NMS scan, truncated to valid tiles. Mdiag staged fully
// in LDS upfront (64 KB) so the serial closure chain never waits on global.
// ---------------------------------------------------------------------------
__global__ __launch_bounds__(128) void nms_scan(
    const u64* __restrict__ M, const u64* __restrict__ Mdiag,
    const int* __restrict__ order,
    const int* __restrict__ svalid, float* __restrict__ outKeep) {
  __shared__ __align__(16) u64 sMdiag[8000];   // 64 KB: 125 tiles x 64 rows
  __shared__ u64 acc[126];
  __shared__ unsigned char klist[64];
  __shared__ int kcount;
  __shared__ int tv[125];
  __shared__ int nvt_s;
  const int tid = threadIdx.x;
  for (int i = tid; i < 4000; i += 128)
    ((float4*)sMdiag)[i] = ((const float4*)Mdiag)[i];
  for (int w = tid; w < 125; w += 128) acc[w] = 0;
  if (tid < 125) tv[tid] = svalid[tid * 64];
  __syncthreads();
  if (tid == 0) {
    int c = 0;
    while (c < 125 && tv[c]) ++c;
    nvt_s = c;
  }
  __syncthreads();
  const int nvt = nvt_s;

  for (int t = 0; t < nvt; ++t) {
    if (tid < 64) {  // wave 0: uniform scalar closure via readlane
      u64 myrow = sMdiag[t * 64 + tid];
      unsigned mlo = (unsigned)myrow, mhi = (unsigned)(myrow >> 32);
      u64 r = acc[t];
      for (int i = 0; i < 64; ++i) {
        u64 take = ((r >> i) & 1ULL) - 1ULL;    // all-ones iff bit i clear
        unsigned rlo = (unsigned)__builtin_amdgcn_readlane((int)mlo, i);
        unsigned rhi = (unsigned)__builtin_amdgcn_readlane((int)mhi, i);
        r |= (((u64)rhi << 32) | (u64)rlo) & take;
      }
      u64 kept = ~r;
      if (tid == 0) { acc[t] = r; kcount = (int)__popcll(kept); }
      if ((kept >> tid) & 1ULL)
        klist[__popcll(kept & ((1ULL << tid) - 1ULL))] = (unsigned char)tid;
    }
    __syncthreads();
    const int kc = kcount;
    const int w = t + 1 + tid;
    if (w < nvt) {
      u64 a = acc[w];
      const u64* base = M + (size_t)t * 64 * 128 + w;
      int j = 0;
      for (; j + 16 <= kc; j += 16) {   // 16 outstanding loads
        u64 o = 0;
#pragma unroll
        for (int q = 0; q < 16; ++q) o |= base[(size_t)klist[j + q] * 128];
        a |= o;
      }
      for (; j + 4 <= kc; j += 4) {
        u64 v0 = base[(size_t)klist[j] * 128];
        u64 v1 = base[(size_t)klist[j + 1] * 128];
        u64 v2 = base[(size_t)klist[j + 2] * 128];
        u64 v3 = base[(size_t)klist[j + 3] * 128];
        a |= (v0 | v1) | (v2 | v3);
      }
      for (; j < kc; ++j) a |= base[(size_t)klist[j] * 128];
      acc[w] = a;
    }
    __syncthreads();
  }

  for (int p = tid; p < 8000; p += 128) {
    int removed = (int)((acc[p >> 6] >> (p & 63)) & 1ULL);
    float kv = (!removed && svalid[p]) ? 1.0f : 0.0f;
    outKeep[order[p]] = kv;
  }
}

// ---------------------------------------------------------------------------
extern "C" void kernel_launch(void* const* d_in, const int* in_sizes, int n_in,
                              void* d_out, int out_size, void* d_ws, size_t ws_size,
                              hipStream_t stream) {
  const float* F    = (const float*)d_in[0];
  const float* ROIS = (const float*)d_in[1];
  const float* W6   = (const float*)d_in[2];
  const float* B6   = (const float*)d_in[3];
  const float* W7   = (const float*)d_in[4];
  const float* B7   = (const float*)d_in[5];
  const float* WC   = (const float*)d_in[6];
  const float* BC   = (const float*)d_in[7];
  const float* WR   = (const float*)d_in[8];
  const float* BR   = (const float*)d_in[9];

  const size_t N = 8000, D = 12544, H = 1024;
  char* ws = (char*)d_ws;
  size_t off = 0;
  auto alloc = [&](size_t bytes) -> void* {
    void* p = (void*)(ws + off);
    off += (bytes + 255) & ~(size_t)255;
    return p;
  };
  f16*   B1w   = (f16*)alloc(H * D * 2);
  f16*   B2w   = (f16*)alloc(H * D * 2);
  f16*   V61   = (f16*)alloc(N * H * 2);
  f16*   V62   = (f16*)alloc(N * H * 2);
  f16*   W71   = (f16*)alloc(H * H * 2);
  f16*   W72   = (f16*)alloc(H * H * 2);
  float* V7    = (float*)alloc(N * H * 4);
  float* SMASK = (float*)alloc(N * 4);
  float* WSBOX = (float*)alloc(N * 16);
  int*   WSVAL = (int*)alloc(N * 4);
  int*   ORDER = (int*)alloc(N * 4);
  float* SBOX  = (float*)alloc(N * 16);
  int*   SVAL  = (int*)alloc(N * 4);
  u64*   MM    = (u64*)alloc(N * 128 * 8);
  u64*   MDIAG = (u64*)alloc(125 * 64 * 8);

  float* outScores  = (float*)d_out;
  float* outClasses = (float*)d_out + 8000;
  float* outBoxes   = (float*)d_out + 16000;
  float* outKeep    = (float*)d_out + 48000;

  split_kernel<<<1024, 256, 0, stream>>>(W6, B1w, B2w, (long)(H * D / 4), 256.0f);
  split_kernel<<<256, 256, 0, stream>>>(W7, W71, W72, (long)(H * H / 4), 256.0f);

  gemm_split<1, 1><<<dim3(8, 32), 512, 0, stream>>>(F, nullptr, B1w, B2w, B6, V61, V62, 8000, 12544);
  gemm_split<2, 0><<<dim3(8, 32), 512, 0, stream>>>(V61, V62, W71, W72, B7, V7, nullptr, 8000, 1024);

  head_final<<<2000, 256, 0, stream>>>(V7, WC, BC, WR, BR, ROIS,
                                       outScores, outClasses, outBoxes,
                                       SMASK, WSBOX, WSVAL);
  rank_kernel<<<32, 256, 0, stream>>>(SMASK, WSBOX, WSVAL, ORDER, SBOX, SVAL);
  iou_matrix<<<dim3(32, 125), 256, 0, stream>>>(SBOX, MM, MDIAG, SVAL);
  nms_scan<<<1, 128, 0, stream>>>(MM, MDIAG, ORDER, SVAL, outKeep);
}

// Round 11
// 1169.049 us; speedup vs baseline: 1.2744x; 1.1711x over previous
//
#include <hip/hip_runtime.h>
#include <hip/hip_fp16.h>
#include <math.h>

typedef _Float16 f16;
typedef _Float16 f16x4 __attribute__((ext_vector_type(4)));
typedef _Float16 f16x8 __attribute__((ext_vector_type(8)));
typedef float f32x4 __attribute__((ext_vector_type(4)));
typedef unsigned long long u64;

// async global->LDS, 16B per lane; LDS dest must be wave-uniform base (HW adds lane*16)
#define GLD16(g, s) __builtin_amdgcn_global_load_lds( \
    (const __attribute__((address_space(1))) void*)(g), \
    (__attribute__((address_space(3))) void*)(s), 16, 0, 0)

// trunc+RNE split: hi = f16(x mantissa-truncated to 13 bits) [exact cast in
// range], lo = RNE(e - em). absmax ~4e-3 measured.
struct HL { f16 h, l; };
__device__ __forceinline__ HL split1(float e) {
  float em = __uint_as_float(__float_as_uint(e) & 0xFFFFE000u);
  HL r;
  r.h = (f16)em;
  r.l = (f16)(e - em);
  return r;
}

// ---------------------------------------------------------------------------
// split fp32 -> (hi, lo) f16 pair, pre-scaled by `scale` (=256). Weights only.
// ---------------------------------------------------------------------------
__global__ __launch_bounds__(256) void split_kernel(const float* __restrict__ src,
                                                    f16* __restrict__ hi,
                                                    f16* __restrict__ lo,
                                                    long n4, float scale) {
  long stride = (long)gridDim.x * blockDim.x;
  for (long i = (long)blockIdx.x * blockDim.x + threadIdx.x; i < n4; i += stride) {
    float4 v = ((const float4*)src)[i];
    f16x4 h, l;
    HL r0 = split1(v.x * scale); h[0] = r0.h; l[0] = r0.l;
    HL r1 = split1(v.y * scale); h[1] = r1.h; l[1] = r1.l;
    HL r2 = split1(v.z * scale); h[2] = r2.h; l[2] = r2.l;
    HL r3 = split1(v.w * scale); h[3] = r3.h; l[3] = r3.l;
    ((f16x4*)hi)[i] = h;
    ((f16x4*)lo)[i] = l;
  }
}

// ---------------------------------------------------------------------------
// Split-precision GEMM, 3-product (hi*hi + lo*hi + hi*lo), 16x16x32 MFMA.
// 256x128 tile, BK=32, 8 waves (4x2), triple-buffered LDS (144 KB).
// AFP32=1: reg-staged A split (T14): fp32 A -> regs (ping-pong S0/S1, depth-2)
//   -> split once/elem -> ds_write into the r7 zero-conflict f16 hi/lo layout.
//   Compute loop = r7's pure-f16 structure (0 LDS conflicts). Split placed
//   post-MFMA (fills MFMA shadow). B via GLD16 depth-2, counted vmcnt(6).
// AFP32=0: r10 path, pre-split f16 hi/lo via GLD16 (unchanged).
// ---------------------------------------------------------------------------
template<int EPI, int AFP32>
__global__ __launch_bounds__(512) void gemm_split(
    const void* __restrict__ Av1, const void* __restrict__ Av2,
    const f16* __restrict__ B1, const f16* __restrict__ B2,
    const float* __restrict__ bias,
    void* __restrict__ out1, void* __restrict__ out2,
    const int M, const int K) {
  // per buffer: A1 16K | A2 16K | B1 8K | B2 8K = 48 KB
  __shared__ __align__(16) char smem[3][49152];
  const int tid = threadIdx.x;           // 0..511
  const int lane = tid & 63;
  const int wid = tid >> 6;              // 0..7
  const int wr = wid >> 1, wcol = wid & 1;
  const int m0 = blockIdx.y * 256;
  const int n0 = blockIdx.x * 128;

  f32x4 acc[4][4];
#pragma unroll
  for (int m = 0; m < 4; ++m)
#pragma unroll
    for (int n = 0; n < 4; ++n) acc[m][n] = (f32x4){0.f, 0.f, 0.f, 0.f};

  // ---- B staging (f16, r7 pattern, 0 conflicts) ----
  const int cg = (((tid & 3) ^ ((tid >> 3) & 3)) * 8);
  const f16* gB1 = B1 + (size_t)(n0 + (tid >> 2)) * K + cg;   // 128 rows
  const f16* gB2 = B2 + (size_t)(n0 + (tid >> 2)) * K + cg;

  // ---- A: reg-staged fp32 (AFP32=1) ----
  // thread owns local rows r0=tid>>2 and r0+128; logical f16-chunk cpl=(tid&3)^sw.
  // LDS write at elem tid*8 (q0) / 4096+tid*8 (q1): position tid&3 of row r0
  // holds global chunk (tid&3)^sw  == the kcA read swizzle's expectation.
  const float* gA0 = nullptr; const float* gA1f = nullptr;
  if (AFP32) {
    const float* Af = (const float*)Av1;
    const int r0 = tid >> 2;
    const int sw = (r0 >> 1) & 3;
    const int cpl = (tid & 3) ^ sw;
    int gr0 = m0 + r0;        if (gr0 > M - 1) gr0 = M - 1;
    int gr1 = m0 + 128 + r0;  if (gr1 > M - 1) gr1 = M - 1;
    gA0  = Af + (size_t)gr0 * K + cpl * 8;
    gA1f = Af + (size_t)gr1 * K + cpl * 8;
  }
  // ---- A: pre-split f16 (AFP32=0) ----
  const f16 *gA1q0 = nullptr, *gA1q1 = nullptr, *gA2q0 = nullptr, *gA2q1 = nullptr;
  if (!AFP32) {
    int ra0 = m0 + (tid >> 2);       if (ra0 > M - 1) ra0 = M - 1;
    int ra1 = m0 + 128 + (tid >> 2); if (ra1 > M - 1) ra1 = M - 1;
    gA1q0 = (const f16*)Av1 + (size_t)ra0 * K + cg;
    gA1q1 = (const f16*)Av1 + (size_t)ra1 * K + cg;
    gA2q0 = (const f16*)Av2 + (size_t)ra0 * K + cg;
    gA2q1 = (const f16*)Av2 + (size_t)ra1 * K + cg;
  }

  const int arow = wr * 64 + (lane & 15);                    // + m*16 (swz m-indep)
  const int brow = wcol * 64 + (lane & 15);                  // + n*16
  const int kcA = (((lane >> 4) ^ ((arow >> 1) & 3)) * 8);   // zero-conflict read
  const int kcB = (((lane >> 4) ^ ((brow >> 1) & 3)) * 8);

  const int nt = K / 32;
  int cur = 0;

#define BSTAGE(buf, kt)                                           \
  do {                                                            \
    char* smx_ = smem[buf];                                       \
    GLD16(gB1 + (kt), (f16*)(smx_ + 32768) + wid * 512);          \
    GLD16(gB2 + (kt), (f16*)(smx_ + 40960) + wid * 512);          \
  } while (0)

#define ALOAD(RA, RB, RC, RD, kt)                                 \
  do {                                                            \
    RA = *(const f32x4*)(gA0 + (kt));                             \
    RB = *(const f32x4*)(gA0 + (kt) + 4);                         \
    RC = *(const f32x4*)(gA1f + (kt));                            \
    RD = *(const f32x4*)(gA1f + (kt) + 4);                        \
  } while (0)

#define ASPLIT(RA, RB, RC, RD, buf)                               \
  do {                                                            \
    f16* dd1 = (f16*)smem[buf];                                   \
    f16* dd2 = dd1 + 8192;                                        \
    f16x8 h_, l_;                                                 \
    _Pragma("unroll")                                             \
    for (int j_ = 0; j_ < 4; ++j_) { HL r_ = split1(RA[j_] * 256.0f); h_[j_] = r_.h; l_[j_] = r_.l; } \
    _Pragma("unroll")                                             \
    for (int j_ = 0; j_ < 4; ++j_) { HL r_ = split1(RB[j_] * 256.0f); h_[4 + j_] = r_.h; l_[4 + j_] = r_.l; } \
    *(f16x8*)(dd1 + tid * 8) = h_;                                \
    *(f16x8*)(dd2 + tid * 8) = l_;                                \
    _Pragma("unroll")                                             \
    for (int j_ = 0; j_ < 4; ++j_) { HL r_ = split1(RC[j_] * 256.0f); h_[j_] = r_.h; l_[j_] = r_.l; } \
    _Pragma("unroll")                                             \
    for (int j_ = 0; j_ < 4; ++j_) { HL r_ = split1(RD[j_] * 256.0f); h_[4 + j_] = r_.h; l_[4 + j_] = r_.l; } \
    *(f16x8*)(dd1 + 4096 + tid * 8) = h_;                         \
    *(f16x8*)(dd2 + 4096 + tid * 8) = l_;                         \
  } while (0)

// one K-step for the reg-staged path. Consumes C* (tile t+1 data -> split ->
// buf[nxt]); loads L* <- tile t+2; B GLD16 tile t+2 -> buf[nxt2].
#define GBODY(t_, CA, CB, CC, CD, LA, LB, LC, LD)                    \
  {                                                                  \
    asm volatile("s_waitcnt vmcnt(6)" ::: "memory");                 \
    asm volatile("s_waitcnt lgkmcnt(0)" ::: "memory");               \
    __builtin_amdgcn_s_barrier();                                    \
    __builtin_amdgcn_sched_barrier(0);                               \
    int nxt_ = cur + 1; if (nxt_ >= 3) nxt_ -= 3;                    \
    int nxt2_ = cur + 2; if (nxt2_ >= 3) nxt2_ -= 3;                 \
    const f16* s1_ = (const f16*)smem[cur];                          \
    const f16* s2_ = s1_ + 8192;                                     \
    const f16* sb1_ = (const f16*)(smem[cur] + 32768);               \
    const f16* sb2_ = (const f16*)(smem[cur] + 40960);               \
    f16x8 a1_[4], a2_[4], b1_[4], b2_[4];                            \
    _Pragma("unroll")                                                \
    for (int m_ = 0; m_ < 4; ++m_) {                                 \
      a1_[m_] = *(const f16x8*)&s1_[(arow + m_ * 16) * 32 + kcA];    \
      a2_[m_] = *(const f16x8*)&s2_[(arow + m_ * 16) * 32 + kcA];    \
    }                                                                \
    _Pragma("unroll")                                                \
    for (int n_ = 0; n_ < 4; ++n_) {                                 \
      b1_[n_] = *(const f16x8*)&sb1_[(brow + n_ * 16) * 32 + kcB];   \
      b2_[n_] = *(const f16x8*)&sb2_[(brow + n_ * 16) * 32 + kcB];   \
    }                                                                \
    if ((t_) + 2 < nt) {                                             \
      ALOAD(LA, LB, LC, LD, ((t_) + 2) * 32);                        \
      BSTAGE(nxt2_, ((t_) + 2) * 32);                                \
    }                                                                \
    _Pragma("unroll")                                                \
    for (int m_ = 0; m_ < 4; ++m_)                                   \
      _Pragma("unroll")                                              \
      for (int n_ = 0; n_ < 4; ++n_) {                               \
        acc[m_][n_] = __builtin_amdgcn_mfma_f32_16x16x32_f16(a1_[m_], b1_[n_], acc[m_][n_], 0, 0, 0); \
        acc[m_][n_] = __builtin_amdgcn_mfma_f32_16x16x32_f16(a2_[m_], b1_[n_], acc[m_][n_], 0, 0, 0); \
        acc[m_][n_] = __builtin_amdgcn_mfma_f32_16x16x32_f16(a1_[m_], b2_[n_], acc[m_][n_], 0, 0, 0); \
      }                                                              \
    __builtin_amdgcn_sched_barrier(0);                               \
    if ((t_) + 1 < nt) ASPLIT(CA, CB, CC, CD, nxt_);                 \
    cur = nxt_;                                                      \
  }

  if (AFP32) {
    // ---- reg-staged pipeline (depth-2 A regs, depth-2 B GLD16) ----
    f32x4 A0a, A0b, A0c, A0d, A1a, A1b, A1c, A1d;
    ALOAD(A0a, A0b, A0c, A0d, 0);
    BSTAGE(0, 0);
    asm volatile("s_waitcnt vmcnt(0)" ::: "memory");
    ASPLIT(A0a, A0b, A0c, A0d, 0);
    ALOAD(A1a, A1b, A1c, A1d, 32);
    BSTAGE(1, 32);
    for (int t = 0; t < nt; t += 2) {
      GBODY(t,     A1a, A1b, A1c, A1d, A0a, A0b, A0c, A0d);  // consume tile t+1
      GBODY(t + 1, A0a, A0b, A0c, A0d, A1a, A1b, A1c, A1d);  // consume tile t+2
    }
  } else {
    // ---- r10 pre-split f16 path (GLD16 all, depth-2, vmcnt(6)) ----
#define STAGE(buf, kt)                                            \
  do {                                                            \
    char* smx_ = smem[buf];                                       \
    f16* d1 = (f16*)smx_;                                         \
    f16* d2 = d1 + 8192;                                          \
    GLD16(gA1q0 + (kt), d1 + wid * 512);                          \
    GLD16(gA1q1 + (kt), d1 + 4096 + wid * 512);                   \
    GLD16(gA2q0 + (kt), d2 + wid * 512);                          \
    GLD16(gA2q1 + (kt), d2 + 4096 + wid * 512);                   \
    GLD16(gB1 + (kt), (f16*)(smx_ + 32768) + wid * 512);          \
    GLD16(gB2 + (kt), (f16*)(smx_ + 40960) + wid * 512);          \
  } while (0)
    STAGE(0, 0);
    if (nt > 1) STAGE(1, 32);
    for (int t = 0; t < nt; ++t) {
      if (t + 1 < nt) asm volatile("s_waitcnt vmcnt(6)" ::: "memory");
      else            asm volatile("s_waitcnt vmcnt(0)" ::: "memory");
      asm volatile("s_waitcnt lgkmcnt(0)" ::: "memory");
      __builtin_amdgcn_s_barrier();
      __builtin_amdgcn_sched_barrier(0);

      const char* smx = smem[cur];
      const f16* s1 = (const f16*)smx;
      const f16* s2 = s1 + 8192;
      const f16* sb1 = (const f16*)(smx + 32768);
      const f16* sb2 = (const f16*)(smx + 40960);
      f16x8 a1[4], a2[4], b1[4], b2[4];
#pragma unroll
      for (int m = 0; m < 4; ++m) {
        a1[m] = *(const f16x8*)&s1[(arow + m * 16) * 32 + kcA];
        a2[m] = *(const f16x8*)&s2[(arow + m * 16) * 32 + kcA];
      }
#pragma unroll
      for (int n = 0; n < 4; ++n) {
        b1[n] = *(const f16x8*)&sb1[(brow + n * 16) * 32 + kcB];
        b2[n] = *(const f16x8*)&sb2[(brow + n * 16) * 32 + kcB];
      }

      int pre = cur + 2; if (pre >= 3) pre -= 3;
      if (t + 2 < nt) STAGE(pre, (t + 2) * 32);

#pragma unroll
      for (int m = 0; m < 4; ++m)
#pragma unroll
        for (int n = 0; n < 4; ++n) {
          acc[m][n] = __builtin_amdgcn_mfma_f32_16x16x32_f16(a1[m], b1[n], acc[m][n], 0, 0, 0);
          acc[m][n] = __builtin_amdgcn_mfma_f32_16x16x32_f16(a2[m], b1[n], acc[m][n], 0, 0, 0);
          acc[m][n] = __builtin_amdgcn_mfma_f32_16x16x32_f16(a1[m], b2[n], acc[m][n], 0, 0, 0);
        }
      ++cur; if (cur >= 3) cur = 0;
    }
#undef STAGE
  }
#undef GBODY
#undef ASPLIT
#undef ALOAD
#undef BSTAGE

  // epilogue: D mapping col=lane&15, row=4*(lane>>4)+j (m89-verified)
  const int crow = m0 + wr * 64 + 4 * (lane >> 4);
  const int ccol0 = n0 + wcol * 64 + (lane & 15);
#pragma unroll
  for (int n = 0; n < 4; ++n) {
    const int col = ccol0 + n * 16;
    const float bv = bias[col];
#pragma unroll
    for (int m = 0; m < 4; ++m) {
#pragma unroll
      for (int j = 0; j < 4; ++j) {
        const int row = crow + m * 16 + j;
        if (row < M) {
          float v = acc[m][n][j] * (1.0f / 65536.0f) + bv;
          v = fmaxf(v, 0.0f);
          if (EPI == 1) {
            HL r = split1(v * 256.0f);
            ((f16*)out1)[(size_t)row * 1024 + col] = r.h;
            ((f16*)out2)[(size_t)row * 1024 + col] = r.l;
          } else {
            ((float*)out1)[(size_t)row * 1024 + col] = v;
          }
        }
      }
    }
  }
}

// ---------------------------------------------------------------------------
// Final head: c/r dots (fp32), argmax/scores, per-class delta, box decode+clip
// ---------------------------------------------------------------------------
__device__ __forceinline__ float dot4f(float4 a, float4 b) {
  return a.x * b.x + a.y * b.y + a.z * b.z + a.w * b.w;
}

__global__ __launch_bounds__(256) void head_final(
    const float* __restrict__ v7,
    const float* __restrict__ wc, const float* __restrict__ bc,
    const float* __restrict__ wr, const float* __restrict__ br,
    const float* __restrict__ rois,
    float* __restrict__ outScores, float* __restrict__ outClasses,
    float* __restrict__ outBoxes,
    float* __restrict__ smask, float* __restrict__ wsbox, int* __restrict__ wsval) {
  const int gw = (blockIdx.x * 256 + threadIdx.x) >> 6;
  const int lane = threadIdx.x & 63;
  if (gw >= 8000) return;

  const float4* vr = (const float4*)(v7 + (size_t)gw * 1024);
  float4 x0 = vr[lane], x1 = vr[64 + lane], x2 = vr[128 + lane], x3 = vr[192 + lane];

  float s[20];
#pragma unroll
  for (int o = 0; o < 20; ++o) {
    const float* wrow = (o < 4) ? (wc + o * 1024) : (wr + (o - 4) * 1024);
    const float4* w4 = (const float4*)wrow;
    float a = dot4f(x0, w4[lane]) + dot4f(x1, w4[64 + lane]) +
              dot4f(x2, w4[128 + lane]) + dot4f(x3, w4[192 + lane]);
#pragma unroll
    for (int off = 32; off >= 1; off >>= 1) a += __shfl_xor(a, off);
    s[o] = a + ((o < 4) ? bc[o] : br[o - 4]);
  }

  float best = s[0]; int cls = 0;
  if (s[1] > best) { best = s[1]; cls = 1; }
  if (s[2] > best) { best = s[2]; cls = 2; }
  if (s[3] > best) { best = s[3]; cls = 3; }

  float d0, d1, d2, d3;  // constant indices only (avoid scratch)
  if      (cls == 0) { d0 = s[4];  d1 = s[5];  d2 = s[6];  d3 = s[7];  }
  else if (cls == 1) { d0 = s[8];  d1 = s[9];  d2 = s[10]; d3 = s[11]; }
  else if (cls == 2) { d0 = s[12]; d1 = s[13]; d2 = s[14]; d3 = s[15]; }
  else               { d0 = s[16]; d1 = s[17]; d2 = s[18]; d3 = s[19]; }

  float4 rb = ((const float4*)rois)[gw];
  float w = rb.z - rb.x, h = rb.w - rb.y;
  float cx = rb.x + 0.5f * w, cy = rb.y + 0.5f * h;
  float pcx = cx + d0 * 0.1f * w;
  float pcy = cy + d1 * 0.1f * h;
  float pw = expf(d2 * 0.2f) * w;
  float ph = expf(d3 * 0.2f) * h;
  float bx0 = fminf(fmaxf(pcx - 0.5f * pw, 0.f), 512.f);
  float by0 = fminf(fmaxf(pcy - 0.5f * ph, 0.f), 512.f);
  float bx1 = fminf(fmaxf(pcx + 0.5f * pw, 0.f), 512.f);
  float by1 = fminf(fmaxf(pcy + 0.5f * ph, 0.f), 512.f);

  if (lane == 0) {
    outScores[gw] = best;
    outClasses[gw] = (float)cls;
    outBoxes[gw * 4 + 0] = bx0;
    outBoxes[gw * 4 + 1] = by0;
    outBoxes[gw * 4 + 2] = bx1;
    outBoxes[gw * 4 + 3] = by1;
    int valid = (cls != 3);
    smask[gw] = valid ? best : -INFINITY;
    wsval[gw] = valid;
    float4 bb; bb.x = bx0; bb.y = by0; bb.z = bx1; bb.w = by1;
    ((float4*)wsbox)[gw] = bb;
  }
}

// ---------------------------------------------------------------------------
// Stable descending rank (== argsort(-s) position), then scatter to sorted arrays
// ---------------------------------------------------------------------------
__global__ __launch_bounds__(256) void rank_kernel(
    const float* __restrict__ smask, const float* __restrict__ bx,
    const int* __restrict__ valid,
    int* __restrict__ order, float* __restrict__ sboxes, int* __restrict__ svalid) {
  __shared__ __align__(16) float sS[8000];
  const int tid = threadIdx.x;
  for (int i = tid; i < 8000; i += 256) sS[i] = smask[i];
  __syncthreads();
  const int i = blockIdx.x * 256 + tid;
  if (i >= 8000) return;
  const float si = sS[i];
  int cnt = 0;
  const float4* s4p = (const float4*)sS;
  for (int j4 = 0; j4 < 2000; ++j4) {
    float4 s4 = s4p[j4];
    int jb = j4 * 4;
    cnt += (s4.x > si) || (s4.x == si && (jb + 0) < i);
    cnt += (s4.y > si) || (s4.y == si && (jb + 1) < i);
    cnt += (s4.z > si) || (s4.z == si && (jb + 2) < i);
    cnt += (s4.w > si) || (s4.w == si && (jb + 3) < i);
  }
  order[cnt] = i;
  svalid[cnt] = valid[i];
  ((float4*)sboxes)[cnt] = ((const float4*)bx)[i];
}

// ---------------------------------------------------------------------------
// Suppression bitmask matrix in SORTED order; one (t,w) tile-pair per wave,
// 4 waves/block. Skips all-invalid pairs (same predicate as nms_scan).
// ---------------------------------------------------------------------------
__global__ __launch_bounds__(256) void iou_matrix(const float* __restrict__ sboxes,
                                                  u64* __restrict__ M,
                                                  u64* __restrict__ Mdiag,
                                                  const int* __restrict__ svalid) {
  const int t = blockIdx.y;
  const int w = blockIdx.x * 4 + (threadIdx.x >> 6);
  if (w < t || w >= 125) return;
  if (svalid[t * 64] == 0 || svalid[w * 64] == 0) return;
  const int lane = threadIdx.x & 63;
  const int ri = t * 64 + lane;
  float4 rb = ((const float4*)sboxes)[ri];
  const float ra = (rb.z - rb.x) * (rb.w - rb.y);
  const float4* cb = (const float4*)sboxes + w * 64;
  u64 bits = 0;
#pragma unroll 4
  for (int j = 0; j < 64; ++j) {
    float4 c = cb[j];
    float x1 = fmaxf(rb.x, c.x), y1 = fmaxf(rb.y, c.y);
    float x2 = fminf(rb.z, c.z), y2 = fminf(rb.w, c.w);
    float inter = fmaxf(x2 - x1, 0.f) * fmaxf(y2 - y1, 0.f);
    float ca = (c.z - c.x) * (c.w - c.y);
    float iou = inter / (ra + ca - inter + 1e-8f);
    int gc = w * 64 + j;
    if (iou > 0.2f && gc > ri) bits |= (1ULL << j);
  }
  M[(size_t)ri * 128 + w] = bits;
  if (w == t) Mdiag[(size_t)t * 64 + lane] = bits;
}

// ---------------------------------------------------------------------------
// Sequential greedy NMS scan, truncated to valid tiles. Mdiag staged in LDS.
// Closure: ctz-driven walk over KEPT boxes only (dynamic-index readlane) —
// ~2x fewer dependent iterations than the all-64 walk, identical semantics
// (rows only contain j>i bits; processed in ascending i).
// ---------------------------------------------------------------------------
__global__ __launch_bounds__(128) void nms_scan(
    const u64* __restrict__ M, const u64* __restrict__ Mdiag,
    const int* __restrict__ order,
    const int* __restrict__ svalid, float* __restrict__ outKeep) {
  __shared__ __align__(16) u64 sMdiag[8000];   // 64 KB: 125 tiles x 64 rows
  __shared__ u64 acc[126];
  __shared__ unsigned char klist[64];
  __shared__ int kcount;
  __shared__ int tv[125];
  __shared__ int nvt_s;
  const int tid = threadIdx.x;
  for (int i = tid; i < 4000; i += 128)
    ((float4*)sMdiag)[i] = ((const float4*)Mdiag)[i];
  for (int w = tid; w < 125; w += 128) acc[w] = 0;
  if (tid < 125) tv[tid] = svalid[tid * 64];
  __syncthreads();
  if (tid == 0) {
    int c = 0;
    while (c < 125 && tv[c]) ++c;
    nvt_s = c;
  }
  __syncthreads();
  const int nvt = nvt_s;

  for (int t = 0; t < nvt; ++t) {
    if (tid < 64) {  // wave 0: ctz closure over kept boxes
      u64 myrow = sMdiag[t * 64 + tid];
      unsigned mlo = (unsigned)myrow, mhi = (unsigned)(myrow >> 32);
      u64 r = acc[t];
      u64 rem = ~r;                       // surviving candidates
      while (rem) {
        int i = __builtin_ctzll(rem);     // next kept box
        unsigned rlo = (unsigned)__builtin_amdgcn_readlane((int)mlo, i);
        unsigned rhi = (unsigned)__builtin_amdgcn_readlane((int)mhi, i);
        u64 rowi = ((u64)rhi << 32) | (u64)rlo;
        r |= rowi;
        rem &= ~(rowi | (1ULL << i));
      }
      u64 kept = ~r;
      if (tid == 0) { acc[t] = r; kcount = (int)__popcll(kept); }
      if ((kept >> tid) & 1ULL)
        klist[__popcll(kept & ((1ULL << tid) - 1ULL))] = (unsigned char)tid;
    }
    __syncthreads();
    const int kc = kcount;
    const int w = t + 1 + tid;
    if (w < nvt) {
      u64 a = acc[w];
      const u64* base = M + (size_t)t * 64 * 128 + w;
      int j = 0;
      for (; j + 16 <= kc; j += 16) {   // 16 outstanding loads
        u64 o = 0;
#pragma unroll
        for (int q = 0; q < 16; ++q) o |= base[(size_t)klist[j + q] * 128];
        a |= o;
      }
      for (; j + 4 <= kc; j += 4) {
        u64 v0 = base[(size_t)klist[j] * 128];
        u64 v1 = base[(size_t)klist[j + 1] * 128];
        u64 v2 = base[(size_t)klist[j + 2] * 128];
        u64 v3 = base[(size_t)klist[j + 3] * 128];
        a |= (v0 | v1) | (v2 | v3);
      }
      for (; j < kc; ++j) a |= base[(size_t)klist[j] * 128];
      acc[w] = a;
    }
    __syncthreads();
  }

  for (int p = tid; p < 8000; p += 128) {
    int removed = (int)((acc[p >> 6] >> (p & 63)) & 1ULL);
    float kv = (!removed && svalid[p]) ? 1.0f : 0.0f;
    outKeep[order[p]] = kv;
  }
}

// ---------------------------------------------------------------------------
extern "C" void kernel_launch(void* const* d_in, const int* in_sizes, int n_in,
                              void* d_out, int out_size, void* d_ws, size_t ws_size,
                              hipStream_t stream) {
  const float* F    = (const float*)d_in[0];
  const float* ROIS = (const float*)d_in[1];
  const float* W6   = (const float*)d_in[2];
  const float* B6   = (const float*)d_in[3];
  const float* W7   = (const float*)d_in[4];
  const float* B7   = (const float*)d_in[5];
  const float* WC   = (const float*)d_in[6];
  const float* BC   = (const float*)d_in[7];
  const float* WR   = (const float*)d_in[8];
  const float* BR   = (const float*)d_in[9];

  const size_t N = 8000, D = 12544, H = 1024;
  char* ws = (char*)d_ws;
  size_t off = 0;
  auto alloc = [&](size_t bytes) -> void* {
    void* p = (void*)(ws + off);
    off += (bytes + 255) & ~(size_t)255;
    return p;
  };
  f16*   B1w   = (f16*)alloc(H * D * 2);
  f16*   B2w   = (f16*)alloc(H * D * 2);
  f16*   V61   = (f16*)alloc(N * H * 2);
  f16*   V62   = (f16*)alloc(N * H * 2);
  f16*   W71   = (f16*)alloc(H * H * 2);
  f16*   W72   = (f16*)alloc(H * H * 2);
  float* V7    = (float*)alloc(N * H * 4);
  float* SMASK = (float*)alloc(N * 4);
  float* WSBOX = (float*)alloc(N * 16);
  int*   WSVAL = (int*)alloc(N * 4);
  int*   ORDER = (int*)alloc(N * 4);
  float* SBOX  = (float*)alloc(N * 16);
  int*   SVAL  = (int*)alloc(N * 4);
  u64*   MM    = (u64*)alloc(N * 128 * 8);
  u64*   MDIAG = (u64*)alloc(125 * 64 * 8);

  float* outScores  = (float*)d_out;
  float* outClasses = (float*)d_out + 8000;
  float* outBoxes   = (float*)d_out + 16000;
  float* outKeep    = (float*)d_out + 48000;

  split_kernel<<<1024, 256, 0, stream>>>(W6, B1w, B2w, (long)(H * D / 4), 256.0f);
  split_kernel<<<256, 256, 0, stream>>>(W7, W71, W72, (long)(H * H / 4), 256.0f);

  gemm_split<1, 1><<<dim3(8, 32), 512, 0, stream>>>(F, nullptr, B1w, B2w, B6, V61, V62, 8000, 12544);
  gemm_split<2, 0><<<dim3(8, 32), 512, 0, stream>>>(V61, V62, W71, W72, B7, V7, nullptr, 8000, 1024);

  head_final<<<2000, 256, 0, stream>>>(V7, WC, BC, WR, BR, ROIS,
                                       outScores, outClasses, outBoxes,
                                       SMASK, WSBOX, WSVAL);
  rank_kernel<<<32, 256, 0, stream>>>(SMASK, WSBOX, WSVAL, ORDER, SBOX, SVAL);
  iou_matrix<<<dim3(32, 125), 256, 0, stream>>>(SBOX, MM, MDIAG, SVAL);
  nms_scan<<<1, 128, 0, stream>>>(MM, MDIAG, ORDER, SVAL, outKeep);
}

// Round 12
// 1156.647 us; speedup vs baseline: 1.2881x; 1.0107x over previous
//
#include <hip/hip_runtime.h>
#include <hip/hip_fp16.h>
#include <math.h>

typedef _Float16 f16;
typedef _Float16 f16x4 __attribute__((ext_vector_type(4)));
typedef _Float16 f16x8 __attribute__((ext_vector_type(8)));
typedef float f32x4 __attribute__((ext_vector_type(4)));
typedef unsigned long long u64;

// async global->LDS, 16B per lane; LDS dest must be wave-uniform base (HW adds lane*16)
#define GLD16(g, s) __builtin_amdgcn_global_load_lds( \
    (const __attribute__((address_space(1))) void*)(g), \
    (__attribute__((address_space(3))) void*)(s), 16, 0, 0)

// trunc+RNE split: hi = f16(x mantissa-truncated to 13 bits) [exact cast in
// range], lo = RNE(e - em). absmax ~4e-3 measured.
struct HL { f16 h, l; };
__device__ __forceinline__ HL split1(float e) {
  float em = __uint_as_float(__float_as_uint(e) & 0xFFFFE000u);
  HL r;
  r.h = (f16)em;
  r.l = (f16)(e - em);
  return r;
}

// ---------------------------------------------------------------------------
// split fp32 -> (hi, lo) f16 pair, pre-scaled by `scale` (=256). Weights only.
// ---------------------------------------------------------------------------
__global__ __launch_bounds__(256) void split_kernel(const float* __restrict__ src,
                                                    f16* __restrict__ hi,
                                                    f16* __restrict__ lo,
                                                    long n4, float scale) {
  long stride = (long)gridDim.x * blockDim.x;
  for (long i = (long)blockIdx.x * blockDim.x + threadIdx.x; i < n4; i += stride) {
    float4 v = ((const float4*)src)[i];
    f16x4 h, l;
    HL r0 = split1(v.x * scale); h[0] = r0.h; l[0] = r0.l;
    HL r1 = split1(v.y * scale); h[1] = r1.h; l[1] = r1.l;
    HL r2 = split1(v.z * scale); h[2] = r2.h; l[2] = r2.l;
    HL r3 = split1(v.w * scale); h[3] = r3.h; l[3] = r3.l;
    ((f16x4*)hi)[i] = h;
    ((f16x4*)lo)[i] = l;
  }
}

// ---------------------------------------------------------------------------
// Split-precision GEMM, 3-product (hi*hi + lo*hi + hi*lo), 16x16x32 MFMA.
// 256x128 tile, BK=32, 8 waves (4x2), triple-buffered LDS (144 KB),
// depth-2 prefetch, counted vmcnt(6). r4/r10 schedule: frag loads/cvt first,
// then STAGE prefetch, then MFMA. PRODUCT-MAJOR MFMA ordering: all 16
// independent (m,n) MFMAs of product p before product p+1 — dependent-reuse
// distance 16 insts (~78 cyc) > MFMA latency, kills the 3-deep acc chains.
// AFP32=1: A staged raw fp32 (chunk-XOR c^(row&7)), hi/lo split in registers.
// AFP32=0: A pre-split f16 hi/lo (r7 zero-conflict pattern).
// ---------------------------------------------------------------------------
template<int EPI, int AFP32>
__global__ __launch_bounds__(512) void gemm_split(
    const void* __restrict__ Av1, const void* __restrict__ Av2,
    const f16* __restrict__ B1, const f16* __restrict__ B2,
    const float* __restrict__ bias,
    void* __restrict__ out1, void* __restrict__ out2,
    const int M, const int K) {
  // per buffer: A 32 KB (fp32 256x32 OR f16 hi+lo) | B1 8 KB | B2 8 KB = 48 KB
  __shared__ __align__(16) char smem[3][49152];
  const int tid = threadIdx.x;           // 0..511
  const int lane = tid & 63;
  const int wid = tid >> 6;              // 0..7
  const int wr = wid >> 1, wcol = wid & 1;
  const int m0 = blockIdx.y * 256;
  const int n0 = blockIdx.x * 128;

  f32x4 acc[4][4];
#pragma unroll
  for (int m = 0; m < 4; ++m)
#pragma unroll
    for (int n = 0; n < 4; ++n) acc[m][n] = (f32x4){0.f, 0.f, 0.f, 0.f};

  // ---- B staging (f16, r7 pattern, 0 conflicts) ----
  const int cg = (((tid & 3) ^ ((tid >> 3) & 3)) * 8);
  const f16* gB1 = B1 + (size_t)(n0 + (tid >> 2)) * K + cg;   // 128 rows
  const f16* gB2 = B2 + (size_t)(n0 + (tid >> 2)) * K + cg;

  // ---- A staging ----
  const float* gAf[4];                   // AFP32: fp32 256x32, chunk c^(row&7)
  if (AFP32) {
    const float* Af = (const float*)Av1;
#pragma unroll
    for (int q = 0; q < 4; ++q) {
      int rowg = m0 + q * 64 + (tid >> 3);
      if (rowg > M - 1) rowg = M - 1;
      const int chunkg = (tid & 7) ^ ((tid >> 3) & 7);
      gAf[q] = Af + (size_t)rowg * K + chunkg * 4;
    }
  }
  const f16 *gA1q0 = nullptr, *gA1q1 = nullptr, *gA2q0 = nullptr, *gA2q1 = nullptr;
  if (!AFP32) {
    int ra0 = m0 + (tid >> 2);       if (ra0 > M - 1) ra0 = M - 1;
    int ra1 = m0 + 128 + (tid >> 2); if (ra1 > M - 1) ra1 = M - 1;
    gA1q0 = (const f16*)Av1 + (size_t)ra0 * K + cg;
    gA1q1 = (const f16*)Av1 + (size_t)ra1 * K + cg;
    gA2q0 = (const f16*)Av2 + (size_t)ra0 * K + cg;
    gA2q1 = (const f16*)Av2 + (size_t)ra1 * K + cg;
  }

  const int arow = wr * 64 + (lane & 15);                    // + m*16 (swz m-indep)
  const int brow = wcol * 64 + (lane & 15);                  // + n*16
  const int kcA = (((lane >> 4) ^ ((arow >> 1) & 3)) * 8);   // f16-A read (0-conflict)
  const int kcB = (((lane >> 4) ^ ((brow >> 1) & 3)) * 8);
  const int pA0 = (((lane >> 4) * 2)     ^ (arow & 7)) * 4;  // fp32-A read (r3)
  const int pA1 = (((lane >> 4) * 2 + 1) ^ (arow & 7)) * 4;

  const int nt = K / 32;

#define STAGE(buf, kt)                                            \
  do {                                                            \
    char* smx_ = smem[buf];                                       \
    if (AFP32) {                                                  \
      float* db = (float*)smx_;                                   \
      GLD16(gAf[0] + (kt), db + 0 * 2048 + wid * 256);            \
      GLD16(gAf[1] + (kt), db + 1 * 2048 + wid * 256);            \
      GLD16(gAf[2] + (kt), db + 2 * 2048 + wid * 256);            \
      GLD16(gAf[3] + (kt), db + 3 * 2048 + wid * 256);            \
    } else {                                                      \
      f16* d1 = (f16*)smx_;                                       \
      f16* d2 = d1 + 8192;                                        \
      GLD16(gA1q0 + (kt), d1 + wid * 512);                        \
      GLD16(gA1q1 + (kt), d1 + 4096 + wid * 512);                 \
      GLD16(gA2q0 + (kt), d2 + wid * 512);                        \
      GLD16(gA2q1 + (kt), d2 + 4096 + wid * 512);                 \
    }                                                             \
    GLD16(gB1 + (kt), (f16*)(smx_ + 32768) + wid * 512);          \
    GLD16(gB2 + (kt), (f16*)(smx_ + 40960) + wid * 512);          \
  } while (0)
  // both variants = 6 GLD16/thread.

  STAGE(0, 0);
  if (nt > 1) STAGE(1, 32);
  int cur = 0;

  for (int t = 0; t < nt; ++t) {
    // own STAGE(t) drained (6 = STAGE(t+1) in flight); barrier extends the
    // guarantee across waves. Never drains to 0 mid-loop (T4).
    if (t + 1 < nt) asm volatile("s_waitcnt vmcnt(6)" ::: "memory");
    else            asm volatile("s_waitcnt vmcnt(0)" ::: "memory");
    asm volatile("s_waitcnt lgkmcnt(0)" ::: "memory");
    __builtin_amdgcn_s_barrier();
    __builtin_amdgcn_sched_barrier(0);

    const char* smx = smem[cur];
    f16x8 a1[4], a2[4], b1[4], b2[4];
    if (AFP32) {
      const float* sf = (const float*)smx;
#pragma unroll
      for (int m = 0; m < 4; ++m) {
        const float* rp = sf + (arow + m * 16) * 32;
        f32x4 u = *(const f32x4*)(rp + pA0);   // logical cols 8k..8k+3
        f32x4 v = *(const f32x4*)(rp + pA1);   // logical cols 8k+4..8k+7
        f16x8 h, l;
#pragma unroll
        for (int j = 0; j < 4; ++j) { HL r = split1(u[j] * 256.0f); h[j] = r.h; l[j] = r.l; }
#pragma unroll
        for (int j = 0; j < 4; ++j) { HL r = split1(v[j] * 256.0f); h[4 + j] = r.h; l[4 + j] = r.l; }
        a1[m] = h; a2[m] = l;
      }
    } else {
      const f16* s1 = (const f16*)smx;
      const f16* s2 = s1 + 8192;
#pragma unroll
      for (int m = 0; m < 4; ++m) {
        a1[m] = *(const f16x8*)&s1[(arow + m * 16) * 32 + kcA];
        a2[m] = *(const f16x8*)&s2[(arow + m * 16) * 32 + kcA];
      }
    }
    {
      const f16* sb1 = (const f16*)(smx + 32768);
      const f16* sb2 = (const f16*)(smx + 40960);
#pragma unroll
      for (int n = 0; n < 4; ++n) {
        b1[n] = *(const f16x8*)&sb1[(brow + n * 16) * 32 + kcB];
        b2[n] = *(const f16x8*)&sb2[(brow + n * 16) * 32 + kcB];
      }
    }

    int pre = cur + 2; if (pre >= 3) pre -= 3;
    if (t + 2 < nt) STAGE(pre, (t + 2) * 32);   // r4 placement: after reads

    // product-major: 16 independent MFMAs between dependent acc reuses
#pragma unroll
    for (int m = 0; m < 4; ++m)
#pragma unroll
      for (int n = 0; n < 4; ++n)
        acc[m][n] = __builtin_amdgcn_mfma_f32_16x16x32_f16(a1[m], b1[n], acc[m][n], 0, 0, 0);
#pragma unroll
    for (int m = 0; m < 4; ++m)
#pragma unroll
      for (int n = 0; n < 4; ++n)
        acc[m][n] = __builtin_amdgcn_mfma_f32_16x16x32_f16(a2[m], b1[n], acc[m][n], 0, 0, 0);
#pragma unroll
    for (int m = 0; m < 4; ++m)
#pragma unroll
      for (int n = 0; n < 4; ++n)
        acc[m][n] = __builtin_amdgcn_mfma_f32_16x16x32_f16(a1[m], b2[n], acc[m][n], 0, 0, 0);

    ++cur; if (cur >= 3) cur = 0;
  }
#undef STAGE

  // epilogue: D mapping col=lane&15, row=4*(lane>>4)+j (m89-verified)
  const int crow = m0 + wr * 64 + 4 * (lane >> 4);
  const int ccol0 = n0 + wcol * 64 + (lane & 15);
#pragma unroll
  for (int n = 0; n < 4; ++n) {
    const int col = ccol0 + n * 16;
    const float bv = bias[col];
#pragma unroll
    for (int m = 0; m < 4; ++m) {
#pragma unroll
      for (int j = 0; j < 4; ++j) {
        const int row = crow + m * 16 + j;
        if (row < M) {
          float v = acc[m][n][j] * (1.0f / 65536.0f) + bv;
          v = fmaxf(v, 0.0f);
          if (EPI == 1) {
            HL r = split1(v * 256.0f);
            ((f16*)out1)[(size_t)row * 1024 + col] = r.h;
            ((f16*)out2)[(size_t)row * 1024 + col] = r.l;
          } else {
            ((float*)out1)[(size_t)row * 1024 + col] = v;
          }
        }
      }
    }
  }
}

// ---------------------------------------------------------------------------
// Final head: c/r dots (fp32), argmax/scores, per-class delta, box decode+clip
// ---------------------------------------------------------------------------
__device__ __forceinline__ float dot4f(float4 a, float4 b) {
  return a.x * b.x + a.y * b.y + a.z * b.z + a.w * b.w;
}

__global__ __launch_bounds__(256) void head_final(
    const float* __restrict__ v7,
    const float* __restrict__ wc, const float* __restrict__ bc,
    const float* __restrict__ wr, const float* __restrict__ br,
    const float* __restrict__ rois,
    float* __restrict__ outScores, float* __restrict__ outClasses,
    float* __restrict__ outBoxes,
    float* __restrict__ smask, float* __restrict__ wsbox, int* __restrict__ wsval) {
  const int gw = (blockIdx.x * 256 + threadIdx.x) >> 6;
  const int lane = threadIdx.x & 63;
  if (gw >= 8000) return;

  const float4* vr = (const float4*)(v7 + (size_t)gw * 1024);
  float4 x0 = vr[lane], x1 = vr[64 + lane], x2 = vr[128 + lane], x3 = vr[192 + lane];

  float s[20];
#pragma unroll
  for (int o = 0; o < 20; ++o) {
    const float* wrow = (o < 4) ? (wc + o * 1024) : (wr + (o - 4) * 1024);
    const float4* w4 = (const float4*)wrow;
    float a = dot4f(x0, w4[lane]) + dot4f(x1, w4[64 + lane]) +
              dot4f(x2, w4[128 + lane]) + dot4f(x3, w4[192 + lane]);
#pragma unroll
    for (int off = 32; off >= 1; off >>= 1) a += __shfl_xor(a, off);
    s[o] = a + ((o < 4) ? bc[o] : br[o - 4]);
  }

  float best = s[0]; int cls = 0;
  if (s[1] > best) { best = s[1]; cls = 1; }
  if (s[2] > best) { best = s[2]; cls = 2; }
  if (s[3] > best) { best = s[3]; cls = 3; }

  float d0, d1, d2, d3;  // constant indices only (avoid scratch)
  if      (cls == 0) { d0 = s[4];  d1 = s[5];  d2 = s[6];  d3 = s[7];  }
  else if (cls == 1) { d0 = s[8];  d1 = s[9];  d2 = s[10]; d3 = s[11]; }
  else if (cls == 2) { d0 = s[12]; d1 = s[13]; d2 = s[14]; d3 = s[15]; }
  else               { d0 = s[16]; d1 = s[17]; d2 = s[18]; d3 = s[19]; }

  float4 rb = ((const float4*)rois)[gw];
  float w = rb.z - rb.x, h = rb.w - rb.y;
  float cx = rb.x + 0.5f * w, cy = rb.y + 0.5f * h;
  float pcx = cx + d0 * 0.1f * w;
  float pcy = cy + d1 * 0.1f * h;
  float pw = expf(d2 * 0.2f) * w;
  float ph = expf(d3 * 0.2f) * h;
  float bx0 = fminf(fmaxf(pcx - 0.5f * pw, 0.f), 512.f);
  float by0 = fminf(fmaxf(pcy - 0.5f * ph, 0.f), 512.f);
  float bx1 = fminf(fmaxf(pcx + 0.5f * pw, 0.f), 512.f);
  float by1 = fminf(fmaxf(pcy + 0.5f * ph, 0.f), 512.f);

  if (lane == 0) {
    outScores[gw] = best;
    outClasses[gw] = (float)cls;
    outBoxes[gw * 4 + 0] = bx0;
    outBoxes[gw * 4 + 1] = by0;
    outBoxes[gw * 4 + 2] = bx1;
    outBoxes[gw * 4 + 3] = by1;
    int valid = (cls != 3);
    smask[gw] = valid ? best : -INFINITY;
    wsval[gw] = valid;
    float4 bb; bb.x = bx0; bb.y = by0; bb.z = bx1; bb.w = by1;
    ((float4*)wsbox)[gw] = bb;
  }
}

// ---------------------------------------------------------------------------
// Stable descending rank (== argsort(-s) position), then scatter to sorted arrays
// ---------------------------------------------------------------------------
__global__ __launch_bounds__(256) void rank_kernel(
    const float* __restrict__ smask, const float* __restrict__ bx,
    const int* __restrict__ valid,
    int* __restrict__ order, float* __restrict__ sboxes, int* __restrict__ svalid) {
  __shared__ __align__(16) float sS[8000];
  const int tid = threadIdx.x;
  for (int i = tid; i < 8000; i += 256) sS[i] = smask[i];
  __syncthreads();
  const int i = blockIdx.x * 256 + tid;
  if (i >= 8000) return;
  const float si = sS[i];
  int cnt = 0;
  const float4* s4p = (const float4*)sS;
  for (int j4 = 0; j4 < 2000; ++j4) {
    float4 s4 = s4p[j4];
    int jb = j4 * 4;
    cnt += (s4.x > si) || (s4.x == si && (jb + 0) < i);
    cnt += (s4.y > si) || (s4.y == si && (jb + 1) < i);
    cnt += (s4.z > si) || (s4.z == si && (jb + 2) < i);
    cnt += (s4.w > si) || (s4.w == si && (jb + 3) < i);
  }
  order[cnt] = i;
  svalid[cnt] = valid[i];
  ((float4*)sboxes)[cnt] = ((const float4*)bx)[i];
}

// ---------------------------------------------------------------------------
// Suppression bitmask matrix in SORTED order; one (t,w) tile-pair per wave,
// 4 waves/block. Skips all-invalid pairs (same predicate as nms_scan).
// ---------------------------------------------------------------------------
__global__ __launch_bounds__(256) void iou_matrix(const float* __restrict__ sboxes,
                                                  u64* __restrict__ M,
                                                  u64* __restrict__ Mdiag,
                                                  const int* __restrict__ svalid) {
  const int t = blockIdx.y;
  const int w = blockIdx.x * 4 + (threadIdx.x >> 6);
  if (w < t || w >= 125) return;
  if (svalid[t * 64] == 0 || svalid[w * 64] == 0) return;
  const int lane = threadIdx.x & 63;
  const int ri = t * 64 + lane;
  float4 rb = ((const float4*)sboxes)[ri];
  const float ra = (rb.z - rb.x) * (rb.w - rb.y);
  const float4* cb = (const float4*)sboxes + w * 64;
  u64 bits = 0;
#pragma unroll 4
  for (int j = 0; j < 64; ++j) {
    float4 c = cb[j];
    float x1 = fmaxf(rb.x, c.x), y1 = fmaxf(rb.y, c.y);
    float x2 = fminf(rb.z, c.z), y2 = fminf(rb.w, c.w);
    float inter = fmaxf(x2 - x1, 0.f) * fmaxf(y2 - y1, 0.f);
    float ca = (c.z - c.x) * (c.w - c.y);
    float iou = inter / (ra + ca - inter + 1e-8f);
    int gc = w * 64 + j;
    if (iou > 0.2f && gc > ri) bits |= (1ULL << j);
  }
  M[(size_t)ri * 128 + w] = bits;
  if (w == t) Mdiag[(size_t)t * 64 + lane] = bits;
}

// ---------------------------------------------------------------------------
// Sequential greedy NMS scan, truncated to valid tiles. Mdiag staged in LDS.
// Closure: ctz-driven walk over KEPT boxes only (dynamic-index readlane).
// ---------------------------------------------------------------------------
__global__ __launch_bounds__(128) void nms_scan(
    const u64* __restrict__ M, const u64* __restrict__ Mdiag,
    const int* __restrict__ order,
    const int* __restrict__ svalid, float* __restrict__ outKeep) {
  __shared__ __align__(16) u64 sMdiag[8000];   // 64 KB: 125 tiles x 64 rows
  __shared__ u64 acc[126];
  __shared__ unsigned char klist[64];
  __shared__ int kcount;
  __shared__ int tv[125];
  __shared__ int nvt_s;
  const int tid = threadIdx.x;
  for (int i = tid; i < 4000; i += 128)
    ((float4*)sMdiag)[i] = ((const float4*)Mdiag)[i];
  for (int w = tid; w < 125; w += 128) acc[w] = 0;
  if (tid < 125) tv[tid] = svalid[tid * 64];
  __syncthreads();
  if (tid == 0) {
    int c = 0;
    while (c < 125 && tv[c]) ++c;
    nvt_s = c;
  }
  __syncthreads();
  const int nvt = nvt_s;

  for (int t = 0; t < nvt; ++t) {
    if (tid < 64) {  // wave 0: ctz closure over kept boxes
      u64 myrow = sMdiag[t * 64 + tid];
      unsigned mlo = (unsigned)myrow, mhi = (unsigned)(myrow >> 32);
      u64 r = acc[t];
      u64 rem = ~r;                       // surviving candidates
      while (rem) {
        int i = __builtin_ctzll(rem);     // next kept box
        unsigned rlo = (unsigned)__builtin_amdgcn_readlane((int)mlo, i);
        unsigned rhi = (unsigned)__builtin_amdgcn_readlane((int)mhi, i);
        u64 rowi = ((u64)rhi << 32) | (u64)rlo;
        r |= rowi;
        rem &= ~(rowi | (1ULL << i));
      }
      u64 kept = ~r;
      if (tid == 0) { acc[t] = r; kcount = (int)__popcll(kept); }
      if ((kept >> tid) & 1ULL)
        klist[__popcll(kept & ((1ULL << tid) - 1ULL))] = (unsigned char)tid;
    }
    __syncthreads();
    const int kc = kcount;
    const int w = t + 1 + tid;
    if (w < nvt) {
      u64 a = acc[w];
      const u64* base = M + (size_t)t * 64 * 128 + w;
      int j = 0;
      for (; j + 16 <= kc; j += 16) {   // 16 outstanding loads
        u64 o = 0;
#pragma unroll
        for (int q = 0; q < 16; ++q) o |= base[(size_t)klist[j + q] * 128];
        a |= o;
      }
      for (; j + 4 <= kc; j += 4) {
        u64 v0 = base[(size_t)klist[j] * 128];
        u64 v1 = base[(size_t)klist[j + 1] * 128];
        u64 v2 = base[(size_t)klist[j + 2] * 128];
        u64 v3 = base[(size_t)klist[j + 3] * 128];
        a |= (v0 | v1) | (v2 | v3);
      }
      for (; j < kc; ++j) a |= base[(size_t)klist[j] * 128];
      acc[w] = a;
    }
    __syncthreads();
  }

  for (int p = tid; p < 8000; p += 128) {
    int removed = (int)((acc[p >> 6] >> (p & 63)) & 1ULL);
    float kv = (!removed && svalid[p]) ? 1.0f : 0.0f;
    outKeep[order[p]] = kv;
  }
}

// ---------------------------------------------------------------------------
extern "C" void kernel_launch(void* const* d_in, const int* in_sizes, int n_in,
                              void* d_out, int out_size, void* d_ws, size_t ws_size,
                              hipStream_t stream) {
  const float* F    = (const float*)d_in[0];
  const float* ROIS = (const float*)d_in[1];
  const float* W6   = (const float*)d_in[2];
  const float* B6   = (const float*)d_in[3];
  const float* W7   = (const float*)d_in[4];
  const float* B7   = (const float*)d_in[5];
  const float* WC   = (const float*)d_in[6];
  const float* BC   = (const float*)d_in[7];
  const float* WR   = (const float*)d_in[8];
  const float* BR   = (const float*)d_in[9];

  const size_t N = 8000, D = 12544, H = 1024;
  char* ws = (char*)d_ws;
  size_t off = 0;
  auto alloc = [&](size_t bytes) -> void* {
    void* p = (void*)(ws + off);
    off += (bytes + 255) & ~(size_t)255;
    return p;
  };
  f16*   B1w   = (f16*)alloc(H * D * 2);
  f16*   B2w   = (f16*)alloc(H * D * 2);
  f16*   V61   = (f16*)alloc(N * H * 2);
  f16*   V62   = (f16*)alloc(N * H * 2);
  f16*   W71   = (f16*)alloc(H * H * 2);
  f16*   W72   = (f16*)alloc(H * H * 2);
  float* V7    = (float*)alloc(N * H * 4);
  float* SMASK = (float*)alloc(N * 4);
  float* WSBOX = (float*)alloc(N * 16);
  int*   WSVAL = (int*)alloc(N * 4);
  int*   ORDER = (int*)alloc(N * 4);
  float* SBOX  = (float*)alloc(N * 16);
  int*   SVAL  = (int*)alloc(N * 4);
  u64*   MM    = (u64*)alloc(N * 128 * 8);
  u64*   MDIAG = (u64*)alloc(125 * 64 * 8);

  float* outScores  = (float*)d_out;
  float* outClasses = (float*)d_out + 8000;
  float* outBoxes   = (float*)d_out + 16000;
  float* outKeep    = (float*)d_out + 48000;

  split_kernel<<<1024, 256, 0, stream>>>(W6, B1w, B2w, (long)(H * D / 4), 256.0f);
  split_kernel<<<256, 256, 0, stream>>>(W7, W71, W72, (long)(H * H / 4), 256.0f);

  gemm_split<1, 1><<<dim3(8, 32), 512, 0, stream>>>(F, nullptr, B1w, B2w, B6, V61, V62, 8000, 12544);
  gemm_split<2, 0><<<dim3(8, 32), 512, 0, stream>>>(V61, V62, W71, W72, B7, V7, nullptr, 8000, 1024);

  head_final<<<2000, 256, 0, stream>>>(V7, WC, BC, WR, BR, ROIS,
                                       outScores, outClasses, outBoxes,
                                       SMASK, WSBOX, WSVAL);
  rank_kernel<<<32, 256, 0, stream>>>(SMASK, WSBOX, WSVAL, ORDER, SBOX, SVAL);
  iou_matrix<<<dim3(32, 125), 256, 0, stream>>>(SBOX, MM, MDIAG, SVAL);
  nms_scan<<<1, 128, 0, stream>>>(MM, MDIAG, ORDER, SVAL, outKeep);
}